// Round 6
// baseline (241.485 us; speedup 1.0000x reference)
//
#include <hip/hip_runtime.h>

typedef unsigned short u16;
typedef unsigned int u32;
typedef short s16x8 __attribute__((ext_vector_type(8)));
typedef short s16x4 __attribute__((ext_vector_type(4)));
typedef float f32x4 __attribute__((ext_vector_type(4)));
typedef float f32x16 __attribute__((ext_vector_type(16)));

#define AS1 __attribute__((address_space(1)))
#define AS3 __attribute__((address_space(3)))

__device__ __forceinline__ float bf2f(u16 u) {
    union { unsigned int i; float f; } x; x.i = ((unsigned int)u) << 16; return x.f;
}
__device__ __forceinline__ u16 f2bf(float f) {
    union { float f; unsigned int i; } x; x.f = f;
    unsigned int r = (x.i + 0x7FFFu + ((x.i >> 16) & 1u)) >> 16;
    return (u16)r;
}
__device__ __forceinline__ void storeOut(u16* p, float v) { *p = f2bf(v); }
__device__ __forceinline__ void storeOut(float* p, float v) { *p = v; }
__device__ __forceinline__ float loadIn(const void* p, size_t i, int isf32) {
    return isf32 ? ((const float*)p)[i] : bf2f(((const u16*)p)[i]);
}
__device__ __forceinline__ float fexp2(float x) {
#if __has_builtin(__builtin_amdgcn_exp2f)
    return __builtin_amdgcn_exp2f(x);
#else
    return exp2f(x);
#endif
}
// exchange upper half-lanes of a with lower half-lanes of b (v_permlane32_swap_b32)
__device__ __forceinline__ void plswap(u32& a, u32& b) {
#if __has_builtin(__builtin_amdgcn_permlane32_swap)
    const auto r = __builtin_amdgcn_permlane32_swap(a, b, false, false);
    a = (u32)r[0]; b = (u32)r[1];
#else
    asm("v_permlane32_swap_b32 %0, %1" : "+v"(a), "+v"(b));
#endif
}

// ---------------- runtime dtype detector ---------------------------------------------
__global__ __launch_bounds__(256) void detect_dtype(const u16* __restrict__ x,
                                                    int* __restrict__ flag) {
    __shared__ int cnt[4];
    const int tid = threadIdx.x;
    int c = 0;
    #pragma unroll
    for (int i = 0; i < 4; ++i) {
        const u16 u = x[tid * 4 + i];
        const int e = (u >> 7) & 0xFF;
        c += (e >= 101 && e <= 135) ? 1 : 0;
    }
    #pragma unroll
    for (int m = 1; m < 64; m <<= 1) c += __shfl_xor(c, m, 64);
    if ((tid & 63) == 0) cnt[tid >> 6] = c;
    __syncthreads();
    if (tid == 0) {
        const int t = cnt[0] + cnt[1] + cnt[2] + cnt[3];
        *flag = (t < 800) ? 1 : 0;   // 1 = inputs are float32
    }
}

// ---------------- cond @ w_cond (split-K GEMV, atomicAdd into zeroed f32 ws) ----------
__global__ __launch_bounds__(256) void cond_gemv(const void* __restrict__ cond,
                                                 const void* __restrict__ w,
                                                 float* __restrict__ out,
                                                 const int* __restrict__ flag) {
    const int isf32 = *flag;
    const int d  = blockIdx.x * 256 + threadIdx.x;
    const int n  = blockIdx.y;
    const int k0 = blockIdx.z * 64;
    float acc = 0.f;
    #pragma unroll 8
    for (int k = 0; k < 64; ++k)
        acc += loadIn(cond, n * 1024 + k0 + k, isf32) *
               loadIn(w, (size_t)(k0 + k) * 1024 + d, isf32);
    atomicAdd(out + n * 1024 + d, acc);
}

// ---------------- RMS norm of x with scale = (cond@w_cond + 1) -----------------------
__global__ __launch_bounds__(256) void rmsnorm_x(const void* __restrict__ x,
                                                 const float* __restrict__ scl,
                                                 u16* __restrict__ xn,
                                                 const int* __restrict__ flag) {
    const int isf32 = *flag;
    const int tok = blockIdx.x;
    const int n = tok >> 11;
    u16* orow = xn + (size_t)tok * 1024;
    const int base = threadIdx.x * 4;
    float f0, f1, f2, f3;
    if (isf32) {
        const float4 v = *(const float4*)((const float*)x + (size_t)tok * 1024 + base);
        f0 = v.x; f1 = v.y; f2 = v.z; f3 = v.w;
    } else {
        s16x4 uv = *(const s16x4*)((const u16*)x + (size_t)tok * 1024 + base);
        f0 = bf2f((u16)uv[0]); f1 = bf2f((u16)uv[1]); f2 = bf2f((u16)uv[2]); f3 = bf2f((u16)uv[3]);
    }
    float ss = f0 * f0 + f1 * f1 + f2 * f2 + f3 * f3;
    #pragma unroll
    for (int m = 1; m < 64; m <<= 1) ss += __shfl_xor(ss, m, 64);
    __shared__ float red[4];
    const int wave = threadIdx.x >> 6, lane = threadIdx.x & 63;
    if (lane == 0) red[wave] = ss;
    __syncthreads();
    float ms = (red[0] + red[1] + red[2] + red[3]) * (1.f / 1024.f);
    float rinv = rsqrtf(ms + 1e-6f);
    orow[base + 0] = f2bf(f0 * (scl[n * 1024 + base + 0] + 1.f) * rinv);
    orow[base + 1] = f2bf(f1 * (scl[n * 1024 + base + 1] + 1.f) * rinv);
    orow[base + 2] = f2bf(f2 * (scl[n * 1024 + base + 2] + 1.f) * rinv);
    orow[base + 3] = f2bf(f3 * (scl[n * 1024 + base + 3] + 1.f) * rinv);
}

// ---------------- transpose (src R x C -> dst C x R), dual-dtype read, bf16 out ------
__global__ __launch_bounds__(256) void transpose_bf(const void* __restrict__ src,
                                                    u16* __restrict__ dst, int R, int C,
                                                    const int* __restrict__ flag) {
    const int isf32 = *flag;
    __shared__ u16 t[32][33];
    const int c0 = blockIdx.x * 32, r0 = blockIdx.y * 32;
    const int tx = threadIdx.x & 31, ty = threadIdx.x >> 5;
    #pragma unroll
    for (int i = 0; i < 4; ++i)
        t[ty + i * 8][tx] = f2bf(loadIn(src, (size_t)(r0 + ty + i * 8) * C + c0 + tx, isf32));
    __syncthreads();
    #pragma unroll
    for (int i = 0; i < 4; ++i)
        dst[(size_t)(c0 + ty + i * 8) * R + r0 + tx] = t[tx][ty + i * 8];
}

// ---------------- bf16 GEMM: C[M,N] = A[M,K] * BT[N,K]^T, 128x128 tile, BK=32 --------
template <typename OutT>
__global__ __launch_bounds__(256) void gemm_bt(const u16* __restrict__ A,
                                               const u16* __restrict__ BT,
                                               OutT* __restrict__ C, int Nn, int K) {
    __shared__ u16 As[128 * 32];
    __shared__ u16 Bs[128 * 32];
    const int tid = threadIdx.x;
    const int wave = tid >> 6, lane = tid & 63;
    const int l15 = lane & 15, quad = lane >> 4;
    const int bm0 = blockIdx.y * 128, bn0 = blockIdx.x * 128;
    const int wr = wave >> 1, wc = wave & 1;
    f32x4 acc[4][4] = {};
    const int srow = lane >> 2;
    const int g = (lane & 3) ^ (srow & 3);
    for (int bk = 0; bk < K; bk += 32) {
        __syncthreads();
        #pragma unroll
        for (int p = 0; p < 2; ++p) {
            const int rowl = p * 64 + wave * 16 + srow;
            const u16* ga = A + (size_t)(bm0 + rowl) * K + bk + g * 8;
            u16* la = As + (p * 64 + wave * 16) * 32;
            __builtin_amdgcn_global_load_lds((const AS1 void*)ga, (AS3 void*)la, 16, 0, 0);
            const u16* gb = BT + (size_t)(bn0 + rowl) * K + bk + g * 8;
            u16* lb = Bs + (p * 64 + wave * 16) * 32;
            __builtin_amdgcn_global_load_lds((const AS1 void*)gb, (AS3 void*)lb, 16, 0, 0);
        }
        __syncthreads();
        s16x8 af[4], bfr[4];
        #pragma unroll
        for (int mt = 0; mt < 4; ++mt) {
            const int r = wr * 64 + mt * 16 + l15;
            af[mt] = *(const s16x8*)(As + r * 32 + ((quad ^ (r & 3)) << 3));
        }
        #pragma unroll
        for (int nt = 0; nt < 4; ++nt) {
            const int r = wc * 64 + nt * 16 + l15;
            bfr[nt] = *(const s16x8*)(Bs + r * 32 + ((quad ^ (r & 3)) << 3));
        }
        #pragma unroll
        for (int mt = 0; mt < 4; ++mt)
            #pragma unroll
            for (int nt = 0; nt < 4; ++nt)
                acc[mt][nt] = __builtin_amdgcn_mfma_f32_16x16x32_bf16(af[mt], bfr[nt], acc[mt][nt], 0, 0, 0);
    }
    #pragma unroll
    for (int mt = 0; mt < 4; ++mt)
        #pragma unroll
        for (int nt = 0; nt < 4; ++nt)
            #pragma unroll
            for (int r = 0; r < 4; ++r) {
                const int row = bm0 + wr * 64 + mt * 16 + quad * 4 + r;
                const int col = bn0 + wc * 64 + nt * 16 + l15;
                storeOut(C + (size_t)row * Nn + col, acc[mt][nt][r]);
            }
}

// ---------------- fused per-head q/k RMS+RoPE + V transpose --------------------------
// grid (32 l-tiles, 32 nh), 256 thr. Wave handles 16 tokens (one per iter, lane = e).
// q scaled by s^2/8 * log2(e) so attention softmax uses exp2 with fixed shift.
__global__ __launch_bounds__(256) void qkv_head(const u16* __restrict__ qkv,
                                                const void* __restrict__ pos,
                                                const void* __restrict__ qk_scale,
                                                u16* __restrict__ q_ws,
                                                u16* __restrict__ k_ws,
                                                u16* __restrict__ vtg,
                                                const int* __restrict__ flag) {
    const int isf32 = *flag;
    const int nh = blockIdx.y;
    const int n = nh >> 4, h = nh & 15;
    const int l0 = blockIdx.x * 64;
    const int tid = threadIdx.x;
    const int wave = tid >> 6, lane = tid & 63;

    // per-lane constants (hoisted out of the token loop)
    const float qs = loadIn(qk_scale, h, isf32);
    const float s = __expf(0.5f * fminf(qs, 4.605170186f) - 1.039720771f);
    const float qmul = s * s * 0.125f * 1.44269504089f;
    const int j = lane & 31;
    const float t = (float)((j & 15) * 16 + h);
    const float freq = 3.14159265358979f * __expf(t * (2.302585093f / 256.f));
    const int pj = j >> 4;

    #pragma unroll 2
    for (int it = 0; it < 16; ++it) {
        const int l = l0 + wave * 16 + it;
        const int tok = n * 2048 + l;
        const u16* row = qkv + (size_t)tok * 3072;
        float qv = bf2f(row[h * 64 + lane]);
        float kv = bf2f(row[1024 + h * 64 + lane]);
        float q2 = qv * qv, k2 = kv * kv;
        #pragma unroll
        for (int m = 1; m < 64; m <<= 1) { q2 += __shfl_xor(q2, m, 64); k2 += __shfl_xor(k2, m, 64); }
        float qn = qv * rsqrtf(q2 * (1.f / 64.f) + 1e-6f) * qmul;
        float kn = kv * rsqrtf(k2 * (1.f / 64.f) + 1e-6f);
        const float p = loadIn(pos, tok * 2 + pj, isf32);
        const float th = p * freq;
        const float c = __cosf(th), sn = __sinf(th);
        const float pq = __shfl_xor(qn, 32, 64);
        const float pk = __shfl_xor(kn, 32, 64);
        float qr, kr;
        if (lane < 32) { qr = qn * c - pq * sn; kr = kn * c - pk * sn; }
        else           { qr = qn * c + pq * sn; kr = kn * c + pk * sn; }
        const size_t oidx = ((size_t)nh * 2048 + l) * 64 + lane;
        q_ws[oidx] = f2bf(qr);
        k_ws[oidx] = f2bf(kr);
    }

    // V transpose: 64 l x 64 e tile -> vtg[nh][e][l]
    __shared__ u16 tbuf[64][65];
    const u16* vsrc = qkv + (size_t)(n * 2048 + l0) * 3072 + 2048 + h * 64;
    #pragma unroll
    for (int it = 0; it < 16; ++it) {
        const int idx = it * 256 + tid;
        const int r = idx >> 6, c = idx & 63;
        tbuf[r][c] = vsrc[(size_t)r * 3072 + c];
    }
    __syncthreads();
    u16* dst = vtg + (size_t)nh * 131072 + l0;
    #pragma unroll
    for (int it = 0; it < 16; ++it) {
        const int idx = it * 256 + tid;
        const int er = idx >> 6, lc = idx & 63;
        dst[(size_t)er * 2048 + lc] = tbuf[lc][er];
    }
}

// ---------------- flash attention v11: 2 blocks/CU, desynchronized barriers ----------
// 512 thr (8 waves: wq=wave&3 -> 32 q-rows, ks=wave>>2 -> kt-half), q-tile 128,
// grid (16, 32) = 512 blocks = 2 blocks/CU (LDS 64 KB). 16 chunks of 128 keys,
// double-buffered, counted vmcnt(4) (4 loads/thread/chunk, attn10 arithmetic).
// Round-5 post-mortem: per-SIMD demand = ~33k matrix-cyc + ~47k VALU-cyc of 113k
// measured -> ~30% stall from CORRELATED waves (all 16 waves hit the same chunk
// barrier together; stage-drain + spine latency expose jointly). Fix: two
// barrier-independent blocks per CU so one block's compute covers the other's
// barrier/drain windows. Inner kt body identical to attn10 (proven correct).
// Fixed-shift softmax => k-split partials combine by pure add through LDS.
__global__ __launch_bounds__(512, 4) void attn11(const u16* __restrict__ Q,
                                                 const u16* __restrict__ K,
                                                 const u16* __restrict__ Vtg,
                                                 u16* __restrict__ O) {
    __shared__ u16 Ks[2][128 * 64];   // chunk rows x 64 e (128 B rows), 16 KB/slot
    __shared__ u16 Vt[2][64 * 128];   // 64 e-rows x chunk cols (256 B rows), 16 KB/slot
    const int nh = blockIdx.y;
    const int q0 = blockIdx.x * 128;
    const int tid = threadIdx.x;
    const int wave = tid >> 6, lane = tid & 63;
    const int wq = wave & 3, ks = wave >> 2;
    const int l31 = lane & 31, h = lane >> 5;
    const size_t hb = (size_t)nh * 2048 * 64;
    const u16* Vbase = Vtg + (size_t)nh * 131072;

    // Q fragments (B-operand of 32x32x16: col=q=l31, rows e=kd*16+h*8+0..7)
    s16x8 qf[4];
    #pragma unroll
    for (int kd = 0; kd < 4; ++kd)
        qf[kd] = *(const s16x8*)(Q + hb + (size_t)(q0 + wq * 32 + l31) * 64 + kd * 16 + h * 8);

    f32x16 Oacc[2] = {};
    float lacc = 0.f;

    // stage one 128-key chunk: K 16 KB (2 rounds of 64 rows) + V 16 KB (2 rounds of
    // 32 e-rows) = 4 global_load_lds per thread.
    auto stage = [&](int ch, int slot) {
        const int kb = ch * 128;
        #pragma unroll
        for (int r = 0; r < 2; ++r) {
            const int row = r * 64 + (tid >> 3);
            const int g = (tid & 7) ^ (row & 7);
            __builtin_amdgcn_global_load_lds(
                (const AS1 void*)(K + hb + (size_t)(kb + row) * 64 + g * 8),
                (AS3 void*)(Ks[slot] + (r * 64 + wave * 8) * 64), 16, 0, 0);
        }
        #pragma unroll
        for (int r = 0; r < 2; ++r) {
            const int er = r * 32 + (tid >> 4);
            const int c = tid & 15;
            const int g2 = c ^ (er & 7);
            __builtin_amdgcn_global_load_lds(
                (const AS1 void*)(Vbase + (size_t)er * 2048 + kb + g2 * 8),
                (AS3 void*)(Vt[slot] + (r * 32 + wave * 4) * 128), 16, 0, 0);
        }
    };

    stage(0, 0);

    for (int j = 0; j < 16; ++j) {
        // top barrier: all waves finished reading buf[(j+1)&1] (used by chunk j-1)
        if (j > 0) __builtin_amdgcn_s_barrier();
        if (j < 15) {
            stage(j + 1, (j + 1) & 1);
            // wait for chunk j's 4 loads (oldest); 4 newest (chunk j+1) stay in flight
            asm volatile("s_waitcnt vmcnt(4)" ::: "memory");
        } else {
            asm volatile("s_waitcnt vmcnt(0)" ::: "memory");
        }
        __builtin_amdgcn_sched_barrier(0);
        __builtin_amdgcn_s_barrier();   // all waves' chunk-j rows present in LDS

        const u16* Kt = Ks[j & 1];
        const u16* Vc = Vt[j & 1];

        #pragma unroll
        for (int t = 0; t < 2; ++t) {
            const int kt = ks * 2 + t;   // this wave-group's kt-half (chunk has 4 kt)
            // ---- QK: S^T(32k x 32q) = K-slice * Q^T, contraction e=64 in 4 steps ----
            f32x16 S;
            #pragma unroll
            for (int jj = 0; jj < 16; ++jj) S[jj] = -15.f;
            const int kr = kt * 32 + l31;
            __builtin_amdgcn_s_setprio(1);
            #pragma unroll
            for (int kd = 0; kd < 4; ++kd) {
                const s16x8 kf = *(const s16x8*)(Kt + kr * 64 + ((((kd << 1) + h) ^ (kr & 7)) << 3));
                S = __builtin_amdgcn_mfma_f32_32x32x16_bf16(kf, qf[kd], S, 0, 0, 0);
            }
            __builtin_amdgcn_s_setprio(0);
            // ---- softmax: exp2 (shift -15 in acc init), row-sum partial ----
            float e[16];
            #pragma unroll
            for (int jj = 0; jj < 16; ++jj) e[jj] = fexp2(S[jj]);
            float rs = 0.f;
            #pragma unroll
            for (int jj = 0; jj < 16; ++jj) rs += e[jj];
            lacc += rs;
            // ---- pack P to bf16 pairs + half-swap into PV A-fragments ----
            u32 c[8];
            #pragma unroll
            for (int jj = 0; jj < 8; ++jj)
                asm("v_cvt_pk_bf16_f32 %0, %1, %2" : "=v"(c[jj]) : "v"(e[2 * jj]), "v"(e[2 * jj + 1]));
            plswap(c[0], c[2]);
            plswap(c[1], c[3]);
            plswap(c[4], c[6]);
            plswap(c[5], c[7]);
            union { u32 u[4]; s16x8 v; } pfa, pfb;
            pfa.u[0] = c[0]; pfa.u[1] = c[1]; pfa.u[2] = c[2]; pfa.u[3] = c[3];
            pfb.u[0] = c[4]; pfb.u[1] = c[5]; pfb.u[2] = c[6]; pfb.u[3] = c[7];
            // ---- PV: Oacc(32q x 32e per et) += P(32q x 32k) * V(32k x 32e) ----
            __builtin_amdgcn_s_setprio(1);
            #pragma unroll
            for (int et = 0; et < 2; ++et) {
                const int er = et * 32 + l31;
                #pragma unroll
                for (int kdp = 0; kdp < 2; ++kdp) {
                    const int ch = kt * 4 + kdp * 2 + h;   // 16-chunk V rows (256 B)
                    const s16x8 vf = *(const s16x8*)(Vc + er * 128 + ((ch ^ (er & 7)) << 3));
                    Oacc[et] = __builtin_amdgcn_mfma_f32_32x32x16_bf16(kdp ? pfb.v : pfa.v, vf, Oacc[et], 0, 0, 0);
                }
            }
            __builtin_amdgcn_s_setprio(0);
        }
    }

    // ---- combine the two kt-half groups: pure add (fixed-shift softmax, no max) ----
    __syncthreads();   // all waves done reading Ks/Vt -> safe to overlay
    float (*Osh)[64] = (float(*)[64]) & Ks[0][0];   // 128 q x 64 e f32 = 32 KB
    float* Lsh = (float*)&Vt[0][0];                 // 128 f32
    if (ks == 1) {
        lacc += __shfl_xor(lacc, 32, 64);
        #pragma unroll
        for (int r = 0; r < 16; ++r) {
            const int ql = (r & 3) + 8 * (r >> 2) + 4 * h;
            #pragma unroll
            for (int et = 0; et < 2; ++et)
                Osh[wq * 32 + ql][et * 32 + l31] = Oacc[et][r];
        }
        if (lane < 32) Lsh[wq * 32 + l31] = lacc;
    }
    __syncthreads();
    if (ks == 0) {
        #pragma unroll
        for (int r = 0; r < 16; ++r) {
            const int ql = (r & 3) + 8 * (r >> 2) + 4 * h;
            #pragma unroll
            for (int et = 0; et < 2; ++et)
                Oacc[et][r] += Osh[wq * 32 + ql][et * 32 + l31];
        }
        lacc += __shfl_xor(lacc, 32, 64);
        lacc += Lsh[wq * 32 + l31];   // same value across both lane halves (q = l31)

        // ---- epilogue: normalize, store ----
        const float linv_l = 1.f / lacc;   // lane l31 holds 1/l for q = l31
        const int n = nh >> 4, hh = nh & 15;
        #pragma unroll
        for (int r = 0; r < 16; ++r) {
            const int ql = (r & 3) + 8 * (r >> 2) + 4 * h;   // q-row of D-reg r
            const float linv = __shfl(linv_l, ql, 64);
            const int qrow = q0 + wq * 32 + ql;
            #pragma unroll
            for (int et = 0; et < 2; ++et)
                O[((size_t)n * 2048 + qrow) * 1024 + hh * 64 + et * 32 + l31] = f2bf(Oacc[et][r] * linv);
        }
    }
}

// ---------------- launch --------------------------------------------------------------
extern "C" void kernel_launch(void* const* d_in, const int* in_sizes, int n_in,
                              void* d_out, int out_size, void* d_ws, size_t ws_size,
                              hipStream_t stream) {
    const void* x        = d_in[0];
    const void* pos      = d_in[1];
    const void* cond     = d_in[2];
    const void* w_cond   = d_in[3];
    const void* w_qkv    = d_in[4];
    const void* qk_scale = d_in[5];
    const void* w_out    = d_in[6];

    char* ws = (char*)d_ws;
    constexpr size_t OFS_SCALE = 0;
    constexpr size_t OFS_FLAG  = 8192;
    constexpr size_t OFS_XN    = 16384;
    constexpr size_t OFS_WQKVT = OFS_XN    + 8388608;
    constexpr size_t OFS_WOUTT = OFS_WQKVT + 6291456;
    constexpr size_t OFS_QKV   = OFS_WOUTT + 2097152;
    constexpr size_t OFS_Q     = OFS_QKV   + 25165824;
    constexpr size_t OFS_K     = OFS_Q     + 8388608;
    constexpr size_t OFS_VT    = OFS_K     + 8388608;
    constexpr size_t OFS_O     = OFS_VT    + 8388608;

    float* scale = (float*)(ws + OFS_SCALE);
    int*   flag  = (int*)(ws + OFS_FLAG);
    u16* xn    = (u16*)(ws + OFS_XN);
    u16* wqkvT = (u16*)(ws + OFS_WQKVT);
    u16* woutT = (u16*)(ws + OFS_WOUTT);
    u16* qkv   = (u16*)(ws + OFS_QKV);
    u16* qws   = (u16*)(ws + OFS_Q);
    u16* kws   = (u16*)(ws + OFS_K);
    u16* vtg   = (u16*)(ws + OFS_VT);
    u16* ows   = (u16*)(ws + OFS_O);

    detect_dtype<<<dim3(1), 256, 0, stream>>>((const u16*)x, flag);
    hipMemsetAsync(scale, 0, 2 * 1024 * sizeof(float), stream);
    cond_gemv<<<dim3(4, 2, 16), 256, 0, stream>>>(cond, w_cond, scale, flag);
    rmsnorm_x<<<dim3(4096), 256, 0, stream>>>(x, scale, xn, flag);
    transpose_bf<<<dim3(96, 32), 256, 0, stream>>>(w_qkv, wqkvT, 1024, 3072, flag);
    transpose_bf<<<dim3(32, 32), 256, 0, stream>>>(w_out, woutT, 1024, 1024, flag);
    gemm_bt<u16><<<dim3(24, 32), 256, 0, stream>>>(xn, wqkvT, qkv, 3072, 1024);
    qkv_head<<<dim3(32, 32), 256, 0, stream>>>(qkv, pos, qk_scale, qws, kws, vtg, flag);
    attn11<<<dim3(16, 32), 512, 0, stream>>>(qws, kws, vtg, ows);
    gemm_bt<float><<<dim3(8, 32), 256, 0, stream>>>(ows, woutT, (float*)d_out, 1024, 1024);
}

// Round 7
// 225.148 us; speedup vs baseline: 1.0726x; 1.0726x over previous
//
#include <hip/hip_runtime.h>

typedef unsigned short u16;
typedef unsigned int u32;
typedef short s16x8 __attribute__((ext_vector_type(8)));
typedef short s16x4 __attribute__((ext_vector_type(4)));
typedef float f32x4 __attribute__((ext_vector_type(4)));
typedef float f32x16 __attribute__((ext_vector_type(16)));

#define AS1 __attribute__((address_space(1)))
#define AS3 __attribute__((address_space(3)))

__device__ __forceinline__ float bf2f(u16 u) {
    union { unsigned int i; float f; } x; x.i = ((unsigned int)u) << 16; return x.f;
}
__device__ __forceinline__ u16 f2bf(float f) {
    union { float f; unsigned int i; } x; x.f = f;
    unsigned int r = (x.i + 0x7FFFu + ((x.i >> 16) & 1u)) >> 16;
    return (u16)r;
}
__device__ __forceinline__ void storeOut(u16* p, float v) { *p = f2bf(v); }
__device__ __forceinline__ void storeOut(float* p, float v) { *p = v; }
__device__ __forceinline__ float loadIn(const void* p, size_t i, int isf32) {
    return isf32 ? ((const float*)p)[i] : bf2f(((const u16*)p)[i]);
}
__device__ __forceinline__ float fexp2(float x) {
#if __has_builtin(__builtin_amdgcn_exp2f)
    return __builtin_amdgcn_exp2f(x);
#else
    return exp2f(x);
#endif
}
// exchange upper half-lanes of a with lower half-lanes of b (v_permlane32_swap_b32)
__device__ __forceinline__ void plswap(u32& a, u32& b) {
#if __has_builtin(__builtin_amdgcn_permlane32_swap)
    const auto r = __builtin_amdgcn_permlane32_swap(a, b, false, false);
    a = (u32)r[0]; b = (u32)r[1];
#else
    asm("v_permlane32_swap_b32 %0, %1" : "+v"(a), "+v"(b));
#endif
}

// ---------------- runtime dtype detector ---------------------------------------------
__global__ __launch_bounds__(256) void detect_dtype(const u16* __restrict__ x,
                                                    int* __restrict__ flag) {
    __shared__ int cnt[4];
    const int tid = threadIdx.x;
    int c = 0;
    #pragma unroll
    for (int i = 0; i < 4; ++i) {
        const u16 u = x[tid * 4 + i];
        const int e = (u >> 7) & 0xFF;
        c += (e >= 101 && e <= 135) ? 1 : 0;
    }
    #pragma unroll
    for (int m = 1; m < 64; m <<= 1) c += __shfl_xor(c, m, 64);
    if ((tid & 63) == 0) cnt[tid >> 6] = c;
    __syncthreads();
    if (tid == 0) {
        const int t = cnt[0] + cnt[1] + cnt[2] + cnt[3];
        *flag = (t < 800) ? 1 : 0;   // 1 = inputs are float32
    }
}

// ---------------- cond @ w_cond (split-K GEMV, atomicAdd into zeroed f32 ws) ----------
__global__ __launch_bounds__(256) void cond_gemv(const void* __restrict__ cond,
                                                 const void* __restrict__ w,
                                                 float* __restrict__ out,
                                                 const int* __restrict__ flag) {
    const int isf32 = *flag;
    const int d  = blockIdx.x * 256 + threadIdx.x;
    const int n  = blockIdx.y;
    const int k0 = blockIdx.z * 64;
    float acc = 0.f;
    #pragma unroll 8
    for (int k = 0; k < 64; ++k)
        acc += loadIn(cond, n * 1024 + k0 + k, isf32) *
               loadIn(w, (size_t)(k0 + k) * 1024 + d, isf32);
    atomicAdd(out + n * 1024 + d, acc);
}

// ---------------- RMS norm of x with scale = (cond@w_cond + 1) -----------------------
__global__ __launch_bounds__(256) void rmsnorm_x(const void* __restrict__ x,
                                                 const float* __restrict__ scl,
                                                 u16* __restrict__ xn,
                                                 const int* __restrict__ flag) {
    const int isf32 = *flag;
    const int tok = blockIdx.x;
    const int n = tok >> 11;
    u16* orow = xn + (size_t)tok * 1024;
    const int base = threadIdx.x * 4;
    float f0, f1, f2, f3;
    if (isf32) {
        const float4 v = *(const float4*)((const float*)x + (size_t)tok * 1024 + base);
        f0 = v.x; f1 = v.y; f2 = v.z; f3 = v.w;
    } else {
        s16x4 uv = *(const s16x4*)((const u16*)x + (size_t)tok * 1024 + base);
        f0 = bf2f((u16)uv[0]); f1 = bf2f((u16)uv[1]); f2 = bf2f((u16)uv[2]); f3 = bf2f((u16)uv[3]);
    }
    float ss = f0 * f0 + f1 * f1 + f2 * f2 + f3 * f3;
    #pragma unroll
    for (int m = 1; m < 64; m <<= 1) ss += __shfl_xor(ss, m, 64);
    __shared__ float red[4];
    const int wave = threadIdx.x >> 6, lane = threadIdx.x & 63;
    if (lane == 0) red[wave] = ss;
    __syncthreads();
    float ms = (red[0] + red[1] + red[2] + red[3]) * (1.f / 1024.f);
    float rinv = rsqrtf(ms + 1e-6f);
    s16x4 ov;
    ov[0] = (short)f2bf(f0 * (scl[n * 1024 + base + 0] + 1.f) * rinv);
    ov[1] = (short)f2bf(f1 * (scl[n * 1024 + base + 1] + 1.f) * rinv);
    ov[2] = (short)f2bf(f2 * (scl[n * 1024 + base + 2] + 1.f) * rinv);
    ov[3] = (short)f2bf(f3 * (scl[n * 1024 + base + 3] + 1.f) * rinv);
    *(s16x4*)(orow + base) = ov;
}

// ---------------- transpose (src R x C -> dst C x R), dual-dtype read, bf16 out ------
__global__ __launch_bounds__(256) void transpose_bf(const void* __restrict__ src,
                                                    u16* __restrict__ dst, int R, int C,
                                                    const int* __restrict__ flag) {
    const int isf32 = *flag;
    __shared__ u16 t[32][33];
    const int c0 = blockIdx.x * 32, r0 = blockIdx.y * 32;
    const int tx = threadIdx.x & 31, ty = threadIdx.x >> 5;
    #pragma unroll
    for (int i = 0; i < 4; ++i)
        t[ty + i * 8][tx] = f2bf(loadIn(src, (size_t)(r0 + ty + i * 8) * C + c0 + tx, isf32));
    __syncthreads();
    #pragma unroll
    for (int i = 0; i < 4; ++i)
        dst[(size_t)(c0 + ty + i * 8) * R + r0 + tx] = t[tx][ty + i * 8];
}

// ---------------- bf16 GEMM: C[M,N] = A[M,K] * BT[N,K]^T, 128x128 tile, BK=32 --------
// v2: double-buffered LDS + counted s_waitcnt vmcnt(4) (attn10's proven chunk flow)
// replaces the per-step vmcnt(0) drain of the 2-barrier structure. 4 loads/thread/chunk.
template <typename OutT>
__global__ __launch_bounds__(256) void gemm_bt(const u16* __restrict__ A,
                                               const u16* __restrict__ BT,
                                               OutT* __restrict__ C, int Nn, int K) {
    __shared__ u16 As[2][128 * 32];
    __shared__ u16 Bs[2][128 * 32];
    const int tid = threadIdx.x;
    const int wave = tid >> 6, lane = tid & 63;
    const int l15 = lane & 15, quad = lane >> 4;
    const int bm0 = blockIdx.y * 128, bn0 = blockIdx.x * 128;
    const int wr = wave >> 1, wc = wave & 1;
    f32x4 acc[4][4] = {};
    const int srow = lane >> 2;
    const int g = (lane & 3) ^ (srow & 3);

    // stage one BK=32 chunk into slot: 4 global_load_lds per thread (2 A + 2 B)
    auto stageg = [&](int ck, int slot) {
        const int bk = ck * 32;
        #pragma unroll
        for (int p = 0; p < 2; ++p) {
            const int rowl = p * 64 + wave * 16 + srow;
            const u16* ga = A + (size_t)(bm0 + rowl) * K + bk + g * 8;
            u16* la = As[slot] + (p * 64 + wave * 16) * 32;
            __builtin_amdgcn_global_load_lds((const AS1 void*)ga, (AS3 void*)la, 16, 0, 0);
            const u16* gb = BT + (size_t)(bn0 + rowl) * K + bk + g * 8;
            u16* lb = Bs[slot] + (p * 64 + wave * 16) * 32;
            __builtin_amdgcn_global_load_lds((const AS1 void*)gb, (AS3 void*)lb, 16, 0, 0);
        }
    };

    const int NC = K >> 5;
    stageg(0, 0);
    for (int j = 0; j < NC; ++j) {
        // top barrier: all waves finished reading slot (j+1)&1 (used at chunk j-1)
        if (j > 0) __builtin_amdgcn_s_barrier();
        if (j < NC - 1) {
            stageg(j + 1, (j + 1) & 1);
            // wait for chunk j's 4 loads; the 4 newest (chunk j+1) stay in flight
            asm volatile("s_waitcnt vmcnt(4)" ::: "memory");
        } else {
            asm volatile("s_waitcnt vmcnt(0)" ::: "memory");
        }
        __builtin_amdgcn_sched_barrier(0);
        __builtin_amdgcn_s_barrier();   // chunk j present for all waves

        const u16* Ac = As[j & 1];
        const u16* Bc = Bs[j & 1];
        s16x8 af[4], bfr[4];
        #pragma unroll
        for (int mt = 0; mt < 4; ++mt) {
            const int r = wr * 64 + mt * 16 + l15;
            af[mt] = *(const s16x8*)(Ac + r * 32 + ((quad ^ (r & 3)) << 3));
        }
        #pragma unroll
        for (int nt = 0; nt < 4; ++nt) {
            const int r = wc * 64 + nt * 16 + l15;
            bfr[nt] = *(const s16x8*)(Bc + r * 32 + ((quad ^ (r & 3)) << 3));
        }
        #pragma unroll
        for (int mt = 0; mt < 4; ++mt)
            #pragma unroll
            for (int nt = 0; nt < 4; ++nt)
                acc[mt][nt] = __builtin_amdgcn_mfma_f32_16x16x32_bf16(af[mt], bfr[nt], acc[mt][nt], 0, 0, 0);
    }
    #pragma unroll
    for (int mt = 0; mt < 4; ++mt)
        #pragma unroll
        for (int nt = 0; nt < 4; ++nt)
            #pragma unroll
            for (int r = 0; r < 4; ++r) {
                const int row = bm0 + wr * 64 + mt * 16 + quad * 4 + r;
                const int col = bn0 + wc * 64 + nt * 16 + l15;
                storeOut(C + (size_t)row * Nn + col, acc[mt][nt][r]);
            }
}

// ---------------- fused per-head q/k RMS+RoPE + V transpose --------------------------
// grid (32 l-tiles, 32 nh), 256 thr. Wave handles 16 tokens (one per iter, lane = e).
// q scaled by s^2/8 * log2(e) so attention softmax uses exp2 with fixed shift.
__global__ __launch_bounds__(256) void qkv_head(const u16* __restrict__ qkv,
                                                const void* __restrict__ pos,
                                                const void* __restrict__ qk_scale,
                                                u16* __restrict__ q_ws,
                                                u16* __restrict__ k_ws,
                                                u16* __restrict__ vtg,
                                                const int* __restrict__ flag) {
    const int isf32 = *flag;
    const int nh = blockIdx.y;
    const int n = nh >> 4, h = nh & 15;
    const int l0 = blockIdx.x * 64;
    const int tid = threadIdx.x;
    const int wave = tid >> 6, lane = tid & 63;

    // per-lane constants (hoisted out of the token loop)
    const float qs = loadIn(qk_scale, h, isf32);
    const float s = __expf(0.5f * fminf(qs, 4.605170186f) - 1.039720771f);
    const float qmul = s * s * 0.125f * 1.44269504089f;
    const int j = lane & 31;
    const float t = (float)((j & 15) * 16 + h);
    const float freq = 3.14159265358979f * __expf(t * (2.302585093f / 256.f));
    const int pj = j >> 4;

    #pragma unroll 2
    for (int it = 0; it < 16; ++it) {
        const int l = l0 + wave * 16 + it;
        const int tok = n * 2048 + l;
        const u16* row = qkv + (size_t)tok * 3072;
        float qv = bf2f(row[h * 64 + lane]);
        float kv = bf2f(row[1024 + h * 64 + lane]);
        float q2 = qv * qv, k2 = kv * kv;
        #pragma unroll
        for (int m = 1; m < 64; m <<= 1) { q2 += __shfl_xor(q2, m, 64); k2 += __shfl_xor(k2, m, 64); }
        float qn = qv * rsqrtf(q2 * (1.f / 64.f) + 1e-6f) * qmul;
        float kn = kv * rsqrtf(k2 * (1.f / 64.f) + 1e-6f);
        const float p = loadIn(pos, tok * 2 + pj, isf32);
        const float th = p * freq;
        const float c = __cosf(th), sn = __sinf(th);
        const float pq = __shfl_xor(qn, 32, 64);
        const float pk = __shfl_xor(kn, 32, 64);
        float qr, kr;
        if (lane < 32) { qr = qn * c - pq * sn; kr = kn * c - pk * sn; }
        else           { qr = qn * c + pq * sn; kr = kn * c + pk * sn; }
        const size_t oidx = ((size_t)nh * 2048 + l) * 64 + lane;
        q_ws[oidx] = f2bf(qr);
        k_ws[oidx] = f2bf(kr);
    }

    // V transpose: 64 l x 64 e tile -> vtg[nh][e][l]
    __shared__ u16 tbuf[64][65];
    const u16* vsrc = qkv + (size_t)(n * 2048 + l0) * 3072 + 2048 + h * 64;
    #pragma unroll
    for (int it = 0; it < 16; ++it) {
        const int idx = it * 256 + tid;
        const int r = idx >> 6, c = idx & 63;
        tbuf[r][c] = vsrc[(size_t)r * 3072 + c];
    }
    __syncthreads();
    u16* dst = vtg + (size_t)nh * 131072 + l0;
    #pragma unroll
    for (int it = 0; it < 16; ++it) {
        const int idx = it * 256 + tid;
        const int er = idx >> 6, lc = idx & 63;
        dst[(size_t)er * 2048 + lc] = tbuf[lc][er];
    }
}

// ---------------- flash attention v10: k-split 16-wave, 4 waves/SIMD (best: 47.1us) --
// 1024 thr (16 waves), q-tile 256, grid (8, 32) = 256 blocks = 1/CU.
// Wave = (wq = wave&7 -> q-rows wq*32, ks = wave>>3 -> kt-half). Each 256-key chunk's
// 8 kt split 4/4 between ks groups. Fixed-shift softmax (no running max) => partial
// (Oacc, lacc) combine by PURE ADD through LDS at the end. Chunked 256-key staging,
// dbuf 128 KB, counted vmcnt(4). s_setprio(1) around MFMA clusters.
__global__ __launch_bounds__(1024) void attn10(const u16* __restrict__ Q,
                                               const u16* __restrict__ K,
                                               const u16* __restrict__ Vtg,
                                               u16* __restrict__ O) {
    __shared__ u16 Ks[2][256 * 64];   // chunk rows x 64 e (128 B rows)
    __shared__ u16 Vt[2][64 * 256];   // 64 e-rows x chunk cols (512 B rows)
    const int nh = blockIdx.y;
    const int q0 = blockIdx.x * 256;
    const int tid = threadIdx.x;
    const int wave = tid >> 6, lane = tid & 63;
    const int wq = wave & 7, ks = wave >> 3;
    const int l31 = lane & 31, h = lane >> 5;
    const size_t hb = (size_t)nh * 2048 * 64;
    const u16* Vbase = Vtg + (size_t)nh * 131072;

    // Q fragments (B-operand of 32x32x16: col=q=l31, rows e=kd*16+h*8+0..7)
    s16x8 qf[4];
    #pragma unroll
    for (int kd = 0; kd < 4; ++kd)
        qf[kd] = *(const s16x8*)(Q + hb + (size_t)(q0 + wq * 32 + l31) * 64 + kd * 16 + h * 8);

    f32x16 Oacc[2] = {};
    float lacc = 0.f;

    // stage one 256-key chunk across 16 waves: K 32 KB (2 rounds of 128 rows) +
    // V 32 KB (2 rounds of 32 e-rows) = 4 global_load_lds per thread.
    auto stage = [&](int ch, int slot) {
        const int kb = ch * 256;
        #pragma unroll
        for (int r = 0; r < 2; ++r) {
            const int row = r * 128 + (tid >> 3);
            const int g = (tid & 7) ^ (row & 7);
            __builtin_amdgcn_global_load_lds(
                (const AS1 void*)(K + hb + (size_t)(kb + row) * 64 + g * 8),
                (AS3 void*)(Ks[slot] + (r * 128 + wave * 8) * 64), 16, 0, 0);
        }
        #pragma unroll
        for (int r = 0; r < 2; ++r) {
            const int er = r * 32 + (tid >> 5);
            const int g2 = (lane & 31) ^ (er & 7);
            __builtin_amdgcn_global_load_lds(
                (const AS1 void*)(Vbase + (size_t)er * 2048 + kb + g2 * 8),
                (AS3 void*)(Vt[slot] + (r * 32 + wave * 2) * 256), 16, 0, 0);
        }
    };

    stage(0, 0);

    for (int j = 0; j < 8; ++j) {
        // top barrier: all waves finished reading buf[(j+1)&1] (used by chunk j-1)
        if (j > 0) __builtin_amdgcn_s_barrier();
        if (j < 7) {
            stage(j + 1, (j + 1) & 1);
            // wait for chunk j's 4 loads (oldest); 4 newest (chunk j+1) stay in flight
            asm volatile("s_waitcnt vmcnt(4)" ::: "memory");
        } else {
            asm volatile("s_waitcnt vmcnt(0)" ::: "memory");
        }
        __builtin_amdgcn_sched_barrier(0);
        __builtin_amdgcn_s_barrier();   // all waves' chunk-j rows present in LDS

        const u16* Kt = Ks[j & 1];
        const u16* Vc = Vt[j & 1];

        #pragma unroll 2
        for (int t = 0; t < 4; ++t) {
            const int kt = ks * 4 + t;   // this wave-group's kt-half
            // ---- QK: S^T(32k x 32q) = K-slice * Q^T, contraction e=64 in 4 steps ----
            f32x16 S;
            #pragma unroll
            for (int jj = 0; jj < 16; ++jj) S[jj] = -15.f;
            const int kr = kt * 32 + l31;
            __builtin_amdgcn_s_setprio(1);
            #pragma unroll
            for (int kd = 0; kd < 4; ++kd) {
                const s16x8 kf = *(const s16x8*)(Kt + kr * 64 + ((((kd << 1) + h) ^ (kr & 7)) << 3));
                S = __builtin_amdgcn_mfma_f32_32x32x16_bf16(kf, qf[kd], S, 0, 0, 0);
            }
            __builtin_amdgcn_s_setprio(0);
            // ---- softmax: exp2 (shift -15 in acc init), row-sum partial ----
            float e[16];
            #pragma unroll
            for (int jj = 0; jj < 16; ++jj) e[jj] = fexp2(S[jj]);
            float rs = 0.f;
            #pragma unroll
            for (int jj = 0; jj < 16; ++jj) rs += e[jj];
            lacc += rs;
            // ---- pack P to bf16 pairs + half-swap into PV A-fragments ----
            u32 c[8];
            #pragma unroll
            for (int jj = 0; jj < 8; ++jj)
                asm("v_cvt_pk_bf16_f32 %0, %1, %2" : "=v"(c[jj]) : "v"(e[2 * jj]), "v"(e[2 * jj + 1]));
            plswap(c[0], c[2]);
            plswap(c[1], c[3]);
            plswap(c[4], c[6]);
            plswap(c[5], c[7]);
            union { u32 u[4]; s16x8 v; } pfa, pfb;
            pfa.u[0] = c[0]; pfa.u[1] = c[1]; pfa.u[2] = c[2]; pfa.u[3] = c[3];
            pfb.u[0] = c[4]; pfb.u[1] = c[5]; pfb.u[2] = c[6]; pfb.u[3] = c[7];
            // ---- PV: Oacc(32q x 32e per et) += P(32q x 32k) * V(32k x 32e) ----
            __builtin_amdgcn_s_setprio(1);
            #pragma unroll
            for (int et = 0; et < 2; ++et) {
                const int er = et * 32 + l31;
                #pragma unroll
                for (int kdp = 0; kdp < 2; ++kdp) {
                    const int ch = kt * 4 + kdp * 2 + h;
                    const s16x8 vf = *(const s16x8*)(Vc + er * 256 + ((ch ^ (er & 7)) << 3));
                    Oacc[et] = __builtin_amdgcn_mfma_f32_32x32x16_bf16(kdp ? pfb.v : pfa.v, vf, Oacc[et], 0, 0, 0);
                }
            }
            __builtin_amdgcn_s_setprio(0);
        }
    }

    // ---- combine the two kt-half groups: pure add (fixed-shift softmax, no max) ----
    __syncthreads();   // all waves done reading Ks/Vt -> safe to overlay
    float (*Osh)[512] = (float(*)[512]) & Ks[0][0];   // 32 x 512 f32 = 64 KB
    float* Lsh = (float*)&Vt[0][0];                   // 512 f32
    if (ks == 1) {
        #pragma unroll
        for (int et = 0; et < 2; ++et)
            #pragma unroll
            for (int r = 0; r < 16; ++r)
                Osh[et * 16 + r][wq * 64 + lane] = Oacc[et][r];
        Lsh[wq * 64 + lane] = lacc;
    }
    __syncthreads();
    if (ks == 0) {
        #pragma unroll
        for (int et = 0; et < 2; ++et)
            #pragma unroll
            for (int r = 0; r < 16; ++r)
                Oacc[et][r] += Osh[et * 16 + r][wq * 64 + lane];
        lacc += Lsh[wq * 64 + lane];

        // ---- epilogue: combine row-sums across lane halves, normalize, store ----
        lacc += __shfl_xor(lacc, 32, 64);
        const float linv_l = 1.f / lacc;   // lane l31 holds 1/l for q = l31
        const int n = nh >> 4, hh = nh & 15;
        #pragma unroll
        for (int r = 0; r < 16; ++r) {
            const int ql = (r & 3) + 8 * (r >> 2) + 4 * h;   // q-row of D-reg r
            const float linv = __shfl(linv_l, ql, 64);
            const int qrow = q0 + wq * 32 + ql;
            #pragma unroll
            for (int et = 0; et < 2; ++et)
                O[((size_t)n * 2048 + qrow) * 1024 + hh * 64 + et * 32 + l31] = f2bf(Oacc[et][r] * linv);
        }
    }
}

// ---------------- launch --------------------------------------------------------------
extern "C" void kernel_launch(void* const* d_in, const int* in_sizes, int n_in,
                              void* d_out, int out_size, void* d_ws, size_t ws_size,
                              hipStream_t stream) {
    const void* x        = d_in[0];
    const void* pos      = d_in[1];
    const void* cond     = d_in[2];
    const void* w_cond   = d_in[3];
    const void* w_qkv    = d_in[4];
    const void* qk_scale = d_in[5];
    const void* w_out    = d_in[6];

    char* ws = (char*)d_ws;
    constexpr size_t OFS_SCALE = 0;
    constexpr size_t OFS_FLAG  = 8192;
    constexpr size_t OFS_XN    = 16384;
    constexpr size_t OFS_WQKVT = OFS_XN    + 8388608;
    constexpr size_t OFS_WOUTT = OFS_WQKVT + 6291456;
    constexpr size_t OFS_QKV   = OFS_WOUTT + 2097152;
    constexpr size_t OFS_Q     = OFS_QKV   + 25165824;
    constexpr size_t OFS_K     = OFS_Q     + 8388608;
    constexpr size_t OFS_VT    = OFS_K     + 8388608;
    constexpr size_t OFS_O     = OFS_VT    + 8388608;

    float* scale = (float*)(ws + OFS_SCALE);
    int*   flag  = (int*)(ws + OFS_FLAG);
    u16* xn    = (u16*)(ws + OFS_XN);
    u16* wqkvT = (u16*)(ws + OFS_WQKVT);
    u16* woutT = (u16*)(ws + OFS_WOUTT);
    u16* qkv   = (u16*)(ws + OFS_QKV);
    u16* qws   = (u16*)(ws + OFS_Q);
    u16* kws   = (u16*)(ws + OFS_K);
    u16* vtg   = (u16*)(ws + OFS_VT);
    u16* ows   = (u16*)(ws + OFS_O);

    detect_dtype<<<dim3(1), 256, 0, stream>>>((const u16*)x, flag);
    hipMemsetAsync(scale, 0, 2 * 1024 * sizeof(float), stream);
    cond_gemv<<<dim3(4, 2, 16), 256, 0, stream>>>(cond, w_cond, scale, flag);
    rmsnorm_x<<<dim3(4096), 256, 0, stream>>>(x, scale, xn, flag);
    transpose_bf<<<dim3(96, 32), 256, 0, stream>>>(w_qkv, wqkvT, 1024, 3072, flag);
    transpose_bf<<<dim3(32, 32), 256, 0, stream>>>(w_out, woutT, 1024, 1024, flag);
    gemm_bt<u16><<<dim3(24, 32), 256, 0, stream>>>(xn, wqkvT, qkv, 3072, 1024);
    qkv_head<<<dim3(32, 32), 256, 0, stream>>>(qkv, pos, qk_scale, qws, kws, vtg, flag);
    attn10<<<dim3(8, 32), 1024, 0, stream>>>(qws, kws, vtg, ows);
    gemm_bt<float><<<dim3(8, 32), 256, 0, stream>>>(ows, woutT, (float*)d_out, 1024, 1024);
}

// Round 9
// 222.165 us; speedup vs baseline: 1.0870x; 1.0134x over previous
//
#include <hip/hip_runtime.h>

typedef unsigned short u16;
typedef unsigned int u32;
typedef short s16x8 __attribute__((ext_vector_type(8)));
typedef short s16x4 __attribute__((ext_vector_type(4)));
typedef float f32x4 __attribute__((ext_vector_type(4)));
typedef float f32x16 __attribute__((ext_vector_type(16)));

#define AS1 __attribute__((address_space(1)))
#define AS3 __attribute__((address_space(3)))

__device__ __forceinline__ float bf2f(u16 u) {
    union { unsigned int i; float f; } x; x.i = ((unsigned int)u) << 16; return x.f;
}
__device__ __forceinline__ u16 f2bf(float f) {
    union { float f; unsigned int i; } x; x.f = f;
    unsigned int r = (x.i + 0x7FFFu + ((x.i >> 16) & 1u)) >> 16;
    return (u16)r;
}
__device__ __forceinline__ void storeOut(u16* p, float v) { *p = f2bf(v); }
__device__ __forceinline__ void storeOut(float* p, float v) { *p = v; }
__device__ __forceinline__ float loadIn(const void* p, size_t i, int isf32) {
    return isf32 ? ((const float*)p)[i] : bf2f(((const u16*)p)[i]);
}
__device__ __forceinline__ float fexp2(float x) {
#if __has_builtin(__builtin_amdgcn_exp2f)
    return __builtin_amdgcn_exp2f(x);
#else
    return exp2f(x);
#endif
}
// exchange upper half-lanes of a with lower half-lanes of b (v_permlane32_swap_b32)
__device__ __forceinline__ void plswap(u32& a, u32& b) {
#if __has_builtin(__builtin_amdgcn_permlane32_swap)
    const auto r = __builtin_amdgcn_permlane32_swap(a, b, false, false);
    a = (u32)r[0]; b = (u32)r[1];
#else
    asm("v_permlane32_swap_b32 %0, %1" : "+v"(a), "+v"(b));
#endif
}

// ---------------- runtime dtype detector ---------------------------------------------
__global__ __launch_bounds__(256) void detect_dtype(const u16* __restrict__ x,
                                                    int* __restrict__ flag) {
    __shared__ int cnt[4];
    const int tid = threadIdx.x;
    int c = 0;
    #pragma unroll
    for (int i = 0; i < 4; ++i) {
        const u16 u = x[tid * 4 + i];
        const int e = (u >> 7) & 0xFF;
        c += (e >= 101 && e <= 135) ? 1 : 0;
    }
    #pragma unroll
    for (int m = 1; m < 64; m <<= 1) c += __shfl_xor(c, m, 64);
    if ((tid & 63) == 0) cnt[tid >> 6] = c;
    __syncthreads();
    if (tid == 0) {
        const int t = cnt[0] + cnt[1] + cnt[2] + cnt[3];
        *flag = (t < 800) ? 1 : 0;   // 1 = inputs are float32
    }
}

// ---------------- cond @ w_cond (split-K GEMV, atomicAdd into zeroed f32 ws) ----------
__global__ __launch_bounds__(256) void cond_gemv(const void* __restrict__ cond,
                                                 const void* __restrict__ w,
                                                 float* __restrict__ out,
                                                 const int* __restrict__ flag) {
    const int isf32 = *flag;
    const int d  = blockIdx.x * 256 + threadIdx.x;
    const int n  = blockIdx.y;
    const int k0 = blockIdx.z * 64;
    float acc = 0.f;
    #pragma unroll 8
    for (int k = 0; k < 64; ++k)
        acc += loadIn(cond, n * 1024 + k0 + k, isf32) *
               loadIn(w, (size_t)(k0 + k) * 1024 + d, isf32);
    atomicAdd(out + n * 1024 + d, acc);
}

// ---------------- RMS norm of x with scale = (cond@w_cond + 1) -----------------------
__global__ __launch_bounds__(256) void rmsnorm_x(const void* __restrict__ x,
                                                 const float* __restrict__ scl,
                                                 u16* __restrict__ xn,
                                                 const int* __restrict__ flag) {
    const int isf32 = *flag;
    const int tok = blockIdx.x;
    const int n = tok >> 11;
    u16* orow = xn + (size_t)tok * 1024;
    const int base = threadIdx.x * 4;
    float f0, f1, f2, f3;
    if (isf32) {
        const float4 v = *(const float4*)((const float*)x + (size_t)tok * 1024 + base);
        f0 = v.x; f1 = v.y; f2 = v.z; f3 = v.w;
    } else {
        s16x4 uv = *(const s16x4*)((const u16*)x + (size_t)tok * 1024 + base);
        f0 = bf2f((u16)uv[0]); f1 = bf2f((u16)uv[1]); f2 = bf2f((u16)uv[2]); f3 = bf2f((u16)uv[3]);
    }
    float ss = f0 * f0 + f1 * f1 + f2 * f2 + f3 * f3;
    #pragma unroll
    for (int m = 1; m < 64; m <<= 1) ss += __shfl_xor(ss, m, 64);
    __shared__ float red[4];
    const int wave = threadIdx.x >> 6, lane = threadIdx.x & 63;
    if (lane == 0) red[wave] = ss;
    __syncthreads();
    float ms = (red[0] + red[1] + red[2] + red[3]) * (1.f / 1024.f);
    float rinv = rsqrtf(ms + 1e-6f);
    s16x4 ov;
    ov[0] = (short)f2bf(f0 * (scl[n * 1024 + base + 0] + 1.f) * rinv);
    ov[1] = (short)f2bf(f1 * (scl[n * 1024 + base + 1] + 1.f) * rinv);
    ov[2] = (short)f2bf(f2 * (scl[n * 1024 + base + 2] + 1.f) * rinv);
    ov[3] = (short)f2bf(f3 * (scl[n * 1024 + base + 3] + 1.f) * rinv);
    *(s16x4*)(orow + base) = ov;
}

// ---------------- transpose (src R x C -> dst C x R), dual-dtype read, bf16 out ------
__global__ __launch_bounds__(256) void transpose_bf(const void* __restrict__ src,
                                                    u16* __restrict__ dst, int R, int C,
                                                    const int* __restrict__ flag) {
    const int isf32 = *flag;
    __shared__ u16 t[32][33];
    const int c0 = blockIdx.x * 32, r0 = blockIdx.y * 32;
    const int tx = threadIdx.x & 31, ty = threadIdx.x >> 5;
    #pragma unroll
    for (int i = 0; i < 4; ++i)
        t[ty + i * 8][tx] = f2bf(loadIn(src, (size_t)(r0 + ty + i * 8) * C + c0 + tx, isf32));
    __syncthreads();
    #pragma unroll
    for (int i = 0; i < 4; ++i)
        dst[(size_t)(c0 + ty + i * 8) * R + r0 + tx] = t[tx][ty + i * 8];
}

// ---------------- bf16 GEMM: C[M,N] = A[M,K] * BT[N,K]^T, 128x128 tile, BK=32 --------
// dbuf LDS + counted s_waitcnt vmcnt(4) (attn10's proven chunk flow). 4 loads/thr/chunk.
template <typename OutT>
__global__ __launch_bounds__(256) void gemm_bt(const u16* __restrict__ A,
                                               const u16* __restrict__ BT,
                                               OutT* __restrict__ C, int Nn, int K) {
    __shared__ u16 As[2][128 * 32];
    __shared__ u16 Bs[2][128 * 32];
    const int tid = threadIdx.x;
    const int wave = tid >> 6, lane = tid & 63;
    const int l15 = lane & 15, quad = lane >> 4;
    const int bm0 = blockIdx.y * 128, bn0 = blockIdx.x * 128;
    const int wr = wave >> 1, wc = wave & 1;
    f32x4 acc[4][4] = {};
    const int srow = lane >> 2;
    const int g = (lane & 3) ^ (srow & 3);

    auto stageg = [&](int ck, int slot) {
        const int bk = ck * 32;
        #pragma unroll
        for (int p = 0; p < 2; ++p) {
            const int rowl = p * 64 + wave * 16 + srow;
            const u16* ga = A + (size_t)(bm0 + rowl) * K + bk + g * 8;
            u16* la = As[slot] + (p * 64 + wave * 16) * 32;
            __builtin_amdgcn_global_load_lds((const AS1 void*)ga, (AS3 void*)la, 16, 0, 0);
            const u16* gb = BT + (size_t)(bn0 + rowl) * K + bk + g * 8;
            u16* lb = Bs[slot] + (p * 64 + wave * 16) * 32;
            __builtin_amdgcn_global_load_lds((const AS1 void*)gb, (AS3 void*)lb, 16, 0, 0);
        }
    };

    const int NC = K >> 5;
    stageg(0, 0);
    for (int j = 0; j < NC; ++j) {
        if (j > 0) __builtin_amdgcn_s_barrier();
        if (j < NC - 1) {
            stageg(j + 1, (j + 1) & 1);
            asm volatile("s_waitcnt vmcnt(4)" ::: "memory");
        } else {
            asm volatile("s_waitcnt vmcnt(0)" ::: "memory");
        }
        __builtin_amdgcn_sched_barrier(0);
        __builtin_amdgcn_s_barrier();

        const u16* Ac = As[j & 1];
        const u16* Bc = Bs[j & 1];
        s16x8 af[4], bfr[4];
        #pragma unroll
        for (int mt = 0; mt < 4; ++mt) {
            const int r = wr * 64 + mt * 16 + l15;
            af[mt] = *(const s16x8*)(Ac + r * 32 + ((quad ^ (r & 3)) << 3));
        }
        #pragma unroll
        for (int nt = 0; nt < 4; ++nt) {
            const int r = wc * 64 + nt * 16 + l15;
            bfr[nt] = *(const s16x8*)(Bc + r * 32 + ((quad ^ (r & 3)) << 3));
        }
        #pragma unroll
        for (int mt = 0; mt < 4; ++mt)
            #pragma unroll
            for (int nt = 0; nt < 4; ++nt)
                acc[mt][nt] = __builtin_amdgcn_mfma_f32_16x16x32_bf16(af[mt], bfr[nt], acc[mt][nt], 0, 0, 0);
    }
    #pragma unroll
    for (int mt = 0; mt < 4; ++mt)
        #pragma unroll
        for (int nt = 0; nt < 4; ++nt)
            #pragma unroll
            for (int r = 0; r < 4; ++r) {
                const int row = bm0 + wr * 64 + mt * 16 + quad * 4 + r;
                const int col = bn0 + wc * 64 + nt * 16 + l15;
                storeOut(C + (size_t)row * Nn + col, acc[mt][nt][r]);
            }
}

// ---------------- bf16 GEMM, 128x64 tile (2 blocks/CU for the narrow out-GEMM) -------
// Standalone copy of gemm_bt with a 64-wide B tile: grid x = N/64 -> 512 blocks =
// 2/CU (fixes the 1-block/CU latency hole of C=4096x1024). 3 loads/thr -> vmcnt(3).
// Wave tile 64 x 32 (wr x wc as before, NT=2 column fragments).
template <typename OutT>
__global__ __launch_bounds__(256) void gemm_bt64(const u16* __restrict__ A,
                                                 const u16* __restrict__ BT,
                                                 OutT* __restrict__ C, int Nn, int K) {
    __shared__ u16 As[2][128 * 32];
    __shared__ u16 Bs[2][64 * 32];
    const int tid = threadIdx.x;
    const int wave = tid >> 6, lane = tid & 63;
    const int l15 = lane & 15, quad = lane >> 4;
    const int bm0 = blockIdx.y * 128, bn0 = blockIdx.x * 64;
    const int wr = wave >> 1, wc = wave & 1;
    f32x4 acc[4][2] = {};
    const int srow = lane >> 2;
    const int g = (lane & 3) ^ (srow & 3);

    auto stageg = [&](int ck, int slot) {
        const int bk = ck * 32;
        #pragma unroll
        for (int p = 0; p < 2; ++p) {
            const int rowl = p * 64 + wave * 16 + srow;
            const u16* ga = A + (size_t)(bm0 + rowl) * K + bk + g * 8;
            u16* la = As[slot] + (p * 64 + wave * 16) * 32;
            __builtin_amdgcn_global_load_lds((const AS1 void*)ga, (AS3 void*)la, 16, 0, 0);
        }
        {
            const int rowl = wave * 16 + srow;
            const u16* gb = BT + (size_t)(bn0 + rowl) * K + bk + g * 8;
            u16* lb = Bs[slot] + (wave * 16) * 32;
            __builtin_amdgcn_global_load_lds((const AS1 void*)gb, (AS3 void*)lb, 16, 0, 0);
        }
    };

    const int NC = K >> 5;
    stageg(0, 0);
    for (int j = 0; j < NC; ++j) {
        if (j > 0) __builtin_amdgcn_s_barrier();
        if (j < NC - 1) {
            stageg(j + 1, (j + 1) & 1);
            asm volatile("s_waitcnt vmcnt(3)" ::: "memory");
        } else {
            asm volatile("s_waitcnt vmcnt(0)" ::: "memory");
        }
        __builtin_amdgcn_sched_barrier(0);
        __builtin_amdgcn_s_barrier();

        const u16* Ac = As[j & 1];
        const u16* Bc = Bs[j & 1];
        s16x8 af[4], bfr[2];
        #pragma unroll
        for (int mt = 0; mt < 4; ++mt) {
            const int r = wr * 64 + mt * 16 + l15;
            af[mt] = *(const s16x8*)(Ac + r * 32 + ((quad ^ (r & 3)) << 3));
        }
        #pragma unroll
        for (int nt = 0; nt < 2; ++nt) {
            const int r = wc * 32 + nt * 16 + l15;
            bfr[nt] = *(const s16x8*)(Bc + r * 32 + ((quad ^ (r & 3)) << 3));
        }
        #pragma unroll
        for (int mt = 0; mt < 4; ++mt)
            #pragma unroll
            for (int nt = 0; nt < 2; ++nt)
                acc[mt][nt] = __builtin_amdgcn_mfma_f32_16x16x32_bf16(af[mt], bfr[nt], acc[mt][nt], 0, 0, 0);
    }
    #pragma unroll
    for (int mt = 0; mt < 4; ++mt)
        #pragma unroll
        for (int nt = 0; nt < 2; ++nt)
            #pragma unroll
            for (int r = 0; r < 4; ++r) {
                const int row = bm0 + wr * 64 + mt * 16 + quad * 4 + r;
                const int col = bn0 + wc * 32 + nt * 16 + l15;
                storeOut(C + (size_t)row * Nn + col, acc[mt][nt][r]);
            }
}

// ---------------- fused per-head q/k RMS+RoPE + V transpose --------------------------
// grid (32 l-tiles, 32 nh), 256 thr. Wave handles 16 tokens (one per iter, lane = e).
// q scaled by s^2/8 * log2(e) so attention softmax uses exp2 with fixed shift.
__global__ __launch_bounds__(256) void qkv_head(const u16* __restrict__ qkv,
                                                const void* __restrict__ pos,
                                                const void* __restrict__ qk_scale,
                                                u16* __restrict__ q_ws,
                                                u16* __restrict__ k_ws,
                                                u16* __restrict__ vtg,
                                                const int* __restrict__ flag) {
    const int isf32 = *flag;
    const int nh = blockIdx.y;
    const int n = nh >> 4, h = nh & 15;
    const int l0 = blockIdx.x * 64;
    const int tid = threadIdx.x;
    const int wave = tid >> 6, lane = tid & 63;

    // per-lane constants (hoisted out of the token loop)
    const float qs = loadIn(qk_scale, h, isf32);
    const float s = __expf(0.5f * fminf(qs, 4.605170186f) - 1.039720771f);
    const float qmul = s * s * 0.125f * 1.44269504089f;
    const int j = lane & 31;
    const float t = (float)((j & 15) * 16 + h);
    const float freq = 3.14159265358979f * __expf(t * (2.302585093f / 256.f));
    const int pj = j >> 4;

    #pragma unroll 2
    for (int it = 0; it < 16; ++it) {
        const int l = l0 + wave * 16 + it;
        const int tok = n * 2048 + l;
        const u16* row = qkv + (size_t)tok * 3072;
        float qv = bf2f(row[h * 64 + lane]);
        float kv = bf2f(row[1024 + h * 64 + lane]);
        float q2 = qv * qv, k2 = kv * kv;
        #pragma unroll
        for (int m = 1; m < 64; m <<= 1) { q2 += __shfl_xor(q2, m, 64); k2 += __shfl_xor(k2, m, 64); }
        float qn = qv * rsqrtf(q2 * (1.f / 64.f) + 1e-6f) * qmul;
        float kn = kv * rsqrtf(k2 * (1.f / 64.f) + 1e-6f);
        const float p = loadIn(pos, tok * 2 + pj, isf32);
        const float th = p * freq;
        const float c = __cosf(th), sn = __sinf(th);
        const float pq = __shfl_xor(qn, 32, 64);
        const float pk = __shfl_xor(kn, 32, 64);
        float qr, kr;
        if (lane < 32) { qr = qn * c - pq * sn; kr = kn * c - pk * sn; }
        else           { qr = qn * c + pq * sn; kr = kn * c + pk * sn; }
        const size_t oidx = ((size_t)nh * 2048 + l) * 64 + lane;
        q_ws[oidx] = f2bf(qr);
        k_ws[oidx] = f2bf(kr);
    }

    // V transpose: 64 l x 64 e tile -> vtg[nh][e][l]
    __shared__ u16 tbuf[64][65];
    const u16* vsrc = qkv + (size_t)(n * 2048 + l0) * 3072 + 2048 + h * 64;
    #pragma unroll
    for (int it = 0; it < 16; ++it) {
        const int idx = it * 256 + tid;
        const int r = idx >> 6, c = idx & 63;
        tbuf[r][c] = vsrc[(size_t)r * 3072 + c];
    }
    __syncthreads();
    u16* dst = vtg + (size_t)nh * 131072 + l0;
    #pragma unroll
    for (int it = 0; it < 16; ++it) {
        const int idx = it * 256 + tid;
        const int er = idx >> 6, lc = idx & 63;
        dst[(size_t)er * 2048 + lc] = tbuf[lc][er];
    }
}

// ---------------- flash attention v10: k-split 16-wave, 4 waves/SIMD (best: 47.1us) --
// 1024 thr (16 waves), q-tile 256, grid (8, 32) = 256 blocks = 1/CU.
// Wave = (wq = wave&7 -> q-rows wq*32, ks = wave>>3 -> kt-half). Each 256-key chunk's
// 8 kt split 4/4 between ks groups. Fixed-shift softmax (no running max) => partial
// (Oacc, lacc) combine by PURE ADD through LDS at the end. Chunked 256-key staging,
// dbuf 128 KB, counted vmcnt(4). s_setprio(1) around MFMA clusters.
__global__ __launch_bounds__(1024) void attn10(const u16* __restrict__ Q,
                                               const u16* __restrict__ K,
                                               const u16* __restrict__ Vtg,
                                               u16* __restrict__ O) {
    __shared__ u16 Ks[2][256 * 64];   // chunk rows x 64 e (128 B rows)
    __shared__ u16 Vt[2][64 * 256];   // 64 e-rows x chunk cols (512 B rows)
    const int nh = blockIdx.y;
    const int q0 = blockIdx.x * 256;
    const int tid = threadIdx.x;
    const int wave = tid >> 6, lane = tid & 63;
    const int wq = wave & 7, ks = wave >> 3;
    const int l31 = lane & 31, h = lane >> 5;
    const size_t hb = (size_t)nh * 2048 * 64;
    const u16* Vbase = Vtg + (size_t)nh * 131072;

    // Q fragments (B-operand of 32x32x16: col=q=l31, rows e=kd*16+h*8+0..7)
    s16x8 qf[4];
    #pragma unroll
    for (int kd = 0; kd < 4; ++kd)
        qf[kd] = *(const s16x8*)(Q + hb + (size_t)(q0 + wq * 32 + l31) * 64 + kd * 16 + h * 8);

    f32x16 Oacc[2] = {};
    float lacc = 0.f;

    // stage one 256-key chunk across 16 waves: K 32 KB (2 rounds of 128 rows) +
    // V 32 KB (2 rounds of 32 e-rows) = 4 global_load_lds per thread.
    auto stage = [&](int ch, int slot) {
        const int kb = ch * 256;
        #pragma unroll
        for (int r = 0; r < 2; ++r) {
            const int row = r * 128 + (tid >> 3);
            const int g = (tid & 7) ^ (row & 7);
            __builtin_amdgcn_global_load_lds(
                (const AS1 void*)(K + hb + (size_t)(kb + row) * 64 + g * 8),
                (AS3 void*)(Ks[slot] + (r * 128 + wave * 8) * 64), 16, 0, 0);
        }
        #pragma unroll
        for (int r = 0; r < 2; ++r) {
            const int er = r * 32 + (tid >> 5);
            const int g2 = (lane & 31) ^ (er & 7);
            __builtin_amdgcn_global_load_lds(
                (const AS1 void*)(Vbase + (size_t)er * 2048 + kb + g2 * 8),
                (AS3 void*)(Vt[slot] + (r * 32 + wave * 2) * 256), 16, 0, 0);
        }
    };

    stage(0, 0);

    for (int j = 0; j < 8; ++j) {
        // top barrier: all waves finished reading buf[(j+1)&1] (used by chunk j-1)
        if (j > 0) __builtin_amdgcn_s_barrier();
        if (j < 7) {
            stage(j + 1, (j + 1) & 1);
            // wait for chunk j's 4 loads (oldest); 4 newest (chunk j+1) stay in flight
            asm volatile("s_waitcnt vmcnt(4)" ::: "memory");
        } else {
            asm volatile("s_waitcnt vmcnt(0)" ::: "memory");
        }
        __builtin_amdgcn_sched_barrier(0);
        __builtin_amdgcn_s_barrier();   // all waves' chunk-j rows present in LDS

        const u16* Kt = Ks[j & 1];
        const u16* Vc = Vt[j & 1];

        #pragma unroll 2
        for (int t = 0; t < 4; ++t) {
            const int kt = ks * 4 + t;   // this wave-group's kt-half
            // ---- QK: S^T(32k x 32q) = K-slice * Q^T, contraction e=64 in 4 steps ----
            f32x16 S;
            #pragma unroll
            for (int jj = 0; jj < 16; ++jj) S[jj] = -15.f;
            const int kr = kt * 32 + l31;
            __builtin_amdgcn_s_setprio(1);
            #pragma unroll
            for (int kd = 0; kd < 4; ++kd) {
                const s16x8 kf = *(const s16x8*)(Kt + kr * 64 + ((((kd << 1) + h) ^ (kr & 7)) << 3));
                S = __builtin_amdgcn_mfma_f32_32x32x16_bf16(kf, qf[kd], S, 0, 0, 0);
            }
            __builtin_amdgcn_s_setprio(0);
            // ---- softmax: exp2 (shift -15 in acc init), row-sum partial ----
            float e[16];
            #pragma unroll
            for (int jj = 0; jj < 16; ++jj) e[jj] = fexp2(S[jj]);
            float rs = 0.f;
            #pragma unroll
            for (int jj = 0; jj < 16; ++jj) rs += e[jj];
            lacc += rs;
            // ---- pack P to bf16 pairs + half-swap into PV A-fragments ----
            u32 c[8];
            #pragma unroll
            for (int jj = 0; jj < 8; ++jj)
                asm("v_cvt_pk_bf16_f32 %0, %1, %2" : "=v"(c[jj]) : "v"(e[2 * jj]), "v"(e[2 * jj + 1]));
            plswap(c[0], c[2]);
            plswap(c[1], c[3]);
            plswap(c[4], c[6]);
            plswap(c[5], c[7]);
            union { u32 u[4]; s16x8 v; } pfa, pfb;
            pfa.u[0] = c[0]; pfa.u[1] = c[1]; pfa.u[2] = c[2]; pfa.u[3] = c[3];
            pfb.u[0] = c[4]; pfb.u[1] = c[5]; pfb.u[2] = c[6]; pfb.u[3] = c[7];
            // ---- PV: Oacc(32q x 32e per et) += P(32q x 32k) * V(32k x 32e) ----
            __builtin_amdgcn_s_setprio(1);
            #pragma unroll
            for (int et = 0; et < 2; ++et) {
                const int er = et * 32 + l31;
                #pragma unroll
                for (int kdp = 0; kdp < 2; ++kdp) {
                    const int ch = kt * 4 + kdp * 2 + h;
                    const s16x8 vf = *(const s16x8*)(Vc + er * 256 + ((ch ^ (er & 7)) << 3));
                    Oacc[et] = __builtin_amdgcn_mfma_f32_32x32x16_bf16(kdp ? pfb.v : pfa.v, vf, Oacc[et], 0, 0, 0);
                }
            }
            __builtin_amdgcn_s_setprio(0);
        }
    }

    // ---- combine the two kt-half groups: pure add (fixed-shift softmax, no max) ----
    __syncthreads();   // all waves done reading Ks/Vt -> safe to overlay
    float (*Osh)[512] = (float(*)[512]) & Ks[0][0];   // 32 x 512 f32 = 64 KB
    float* Lsh = (float*)&Vt[0][0];                   // 512 f32
    if (ks == 1) {
        #pragma unroll
        for (int et = 0; et < 2; ++et)
            #pragma unroll
            for (int r = 0; r < 16; ++r)
                Osh[et * 16 + r][wq * 64 + lane] = Oacc[et][r];
        Lsh[wq * 64 + lane] = lacc;
    }
    __syncthreads();
    if (ks == 0) {
        #pragma unroll
        for (int et = 0; et < 2; ++et)
            #pragma unroll
            for (int r = 0; r < 16; ++r)
                Oacc[et][r] += Osh[et * 16 + r][wq * 64 + lane];
        lacc += Lsh[wq * 64 + lane];

        // ---- epilogue: combine row-sums across lane halves, normalize, store ----
        lacc += __shfl_xor(lacc, 32, 64);
        const float linv_l = 1.f / lacc;   // lane l31 holds 1/l for q = l31
        const int n = nh >> 4, hh = nh & 15;
        #pragma unroll
        for (int r = 0; r < 16; ++r) {
            const int ql = (r & 3) + 8 * (r >> 2) + 4 * h;   // q-row of D-reg r
            const float linv = __shfl(linv_l, ql, 64);
            const int qrow = q0 + wq * 32 + ql;
            #pragma unroll
            for (int et = 0; et < 2; ++et)
                O[((size_t)n * 2048 + qrow) * 1024 + hh * 64 + et * 32 + l31] = f2bf(Oacc[et][r] * linv);
        }
    }
}

// ---------------- launch --------------------------------------------------------------
extern "C" void kernel_launch(void* const* d_in, const int* in_sizes, int n_in,
                              void* d_out, int out_size, void* d_ws, size_t ws_size,
                              hipStream_t stream) {
    const void* x        = d_in[0];
    const void* pos      = d_in[1];
    const void* cond     = d_in[2];
    const void* w_cond   = d_in[3];
    const void* w_qkv    = d_in[4];
    const void* qk_scale = d_in[5];
    const void* w_out    = d_in[6];

    char* ws = (char*)d_ws;
    constexpr size_t OFS_SCALE = 0;
    constexpr size_t OFS_FLAG  = 8192;
    constexpr size_t OFS_XN    = 16384;
    constexpr size_t OFS_WQKVT = OFS_XN    + 8388608;
    constexpr size_t OFS_WOUTT = OFS_WQKVT + 6291456;
    constexpr size_t OFS_QKV   = OFS_WOUTT + 2097152;
    constexpr size_t OFS_Q     = OFS_QKV   + 25165824;
    constexpr size_t OFS_K     = OFS_Q     + 8388608;
    constexpr size_t OFS_VT    = OFS_K     + 8388608;
    constexpr size_t OFS_O     = OFS_VT    + 8388608;

    float* scale = (float*)(ws + OFS_SCALE);
    int*   flag  = (int*)(ws + OFS_FLAG);
    u16* xn    = (u16*)(ws + OFS_XN);
    u16* wqkvT = (u16*)(ws + OFS_WQKVT);
    u16* woutT = (u16*)(ws + OFS_WOUTT);
    u16* qkv   = (u16*)(ws + OFS_QKV);
    u16* qws   = (u16*)(ws + OFS_Q);
    u16* kws   = (u16*)(ws + OFS_K);
    u16* vtg   = (u16*)(ws + OFS_VT);
    u16* ows   = (u16*)(ws + OFS_O);

    detect_dtype<<<dim3(1), 256, 0, stream>>>((const u16*)x, flag);
    hipMemsetAsync(scale, 0, 2 * 1024 * sizeof(float), stream);
    cond_gemv<<<dim3(4, 2, 16), 256, 0, stream>>>(cond, w_cond, scale, flag);
    rmsnorm_x<<<dim3(4096), 256, 0, stream>>>(x, scale, xn, flag);
    transpose_bf<<<dim3(96, 32), 256, 0, stream>>>(w_qkv, wqkvT, 1024, 3072, flag);
    transpose_bf<<<dim3(32, 32), 256, 0, stream>>>(w_out, woutT, 1024, 1024, flag);
    gemm_bt<u16><<<dim3(24, 32), 256, 0, stream>>>(xn, wqkvT, qkv, 3072, 1024);
    qkv_head<<<dim3(32, 32), 256, 0, stream>>>(qkv, pos, qk_scale, qws, kws, vtg, flag);
    attn10<<<dim3(8, 32), 1024, 0, stream>>>(qws, kws, vtg, ows);
    gemm_bt64<float><<<dim3(16, 32), 256, 0, stream>>>(ows, woutT, (float*)d_out, 1024, 1024);
}

// Round 10
// 220.905 us; speedup vs baseline: 1.0932x; 1.0057x over previous
//
#include <hip/hip_runtime.h>

typedef unsigned short u16;
typedef unsigned int u32;
typedef short s16x8 __attribute__((ext_vector_type(8)));
typedef short s16x4 __attribute__((ext_vector_type(4)));
typedef float f32x4 __attribute__((ext_vector_type(4)));
typedef float f32x16 __attribute__((ext_vector_type(16)));

#define AS1 __attribute__((address_space(1)))
#define AS3 __attribute__((address_space(3)))

__device__ __forceinline__ float bf2f(u16 u) {
    union { unsigned int i; float f; } x; x.i = ((unsigned int)u) << 16; return x.f;
}
__device__ __forceinline__ u16 f2bf(float f) {
    union { float f; unsigned int i; } x; x.f = f;
    unsigned int r = (x.i + 0x7FFFu + ((x.i >> 16) & 1u)) >> 16;
    return (u16)r;
}
__device__ __forceinline__ void storeOut(u16* p, float v) { *p = f2bf(v); }
__device__ __forceinline__ void storeOut(float* p, float v) { *p = v; }
__device__ __forceinline__ float loadIn(const void* p, size_t i, int isf32) {
    return isf32 ? ((const float*)p)[i] : bf2f(((const u16*)p)[i]);
}
__device__ __forceinline__ float fexp2(float x) {
#if __has_builtin(__builtin_amdgcn_exp2f)
    return __builtin_amdgcn_exp2f(x);
#else
    return exp2f(x);
#endif
}
// exchange upper half-lanes of a with lower half-lanes of b (v_permlane32_swap_b32)
__device__ __forceinline__ void plswap(u32& a, u32& b) {
#if __has_builtin(__builtin_amdgcn_permlane32_swap)
    const auto r = __builtin_amdgcn_permlane32_swap(a, b, false, false);
    a = (u32)r[0]; b = (u32)r[1];
#else
    asm("v_permlane32_swap_b32 %0, %1" : "+v"(a), "+v"(b));
#endif
}

// ---------------- runtime dtype detector ---------------------------------------------
__global__ __launch_bounds__(256) void detect_dtype(const u16* __restrict__ x,
                                                    int* __restrict__ flag) {
    __shared__ int cnt[4];
    const int tid = threadIdx.x;
    int c = 0;
    #pragma unroll
    for (int i = 0; i < 4; ++i) {
        const u16 u = x[tid * 4 + i];
        const int e = (u >> 7) & 0xFF;
        c += (e >= 101 && e <= 135) ? 1 : 0;
    }
    #pragma unroll
    for (int m = 1; m < 64; m <<= 1) c += __shfl_xor(c, m, 64);
    if ((tid & 63) == 0) cnt[tid >> 6] = c;
    __syncthreads();
    if (tid == 0) {
        const int t = cnt[0] + cnt[1] + cnt[2] + cnt[3];
        *flag = (t < 800) ? 1 : 0;   // 1 = inputs are float32
    }
}

// ---------------- cond @ w_cond (split-K GEMV, atomicAdd into zeroed f32 ws) ----------
__global__ __launch_bounds__(256) void cond_gemv(const void* __restrict__ cond,
                                                 const void* __restrict__ w,
                                                 float* __restrict__ out,
                                                 const int* __restrict__ flag) {
    const int isf32 = *flag;
    const int d  = blockIdx.x * 256 + threadIdx.x;
    const int n  = blockIdx.y;
    const int k0 = blockIdx.z * 64;
    float acc = 0.f;
    #pragma unroll 8
    for (int k = 0; k < 64; ++k)
        acc += loadIn(cond, n * 1024 + k0 + k, isf32) *
               loadIn(w, (size_t)(k0 + k) * 1024 + d, isf32);
    atomicAdd(out + n * 1024 + d, acc);
}

// ---------------- RMS norm of x with scale = (cond@w_cond + 1) -----------------------
__global__ __launch_bounds__(256) void rmsnorm_x(const void* __restrict__ x,
                                                 const float* __restrict__ scl,
                                                 u16* __restrict__ xn,
                                                 const int* __restrict__ flag) {
    const int isf32 = *flag;
    const int tok = blockIdx.x;
    const int n = tok >> 11;
    u16* orow = xn + (size_t)tok * 1024;
    const int base = threadIdx.x * 4;
    float f0, f1, f2, f3;
    if (isf32) {
        const float4 v = *(const float4*)((const float*)x + (size_t)tok * 1024 + base);
        f0 = v.x; f1 = v.y; f2 = v.z; f3 = v.w;
    } else {
        s16x4 uv = *(const s16x4*)((const u16*)x + (size_t)tok * 1024 + base);
        f0 = bf2f((u16)uv[0]); f1 = bf2f((u16)uv[1]); f2 = bf2f((u16)uv[2]); f3 = bf2f((u16)uv[3]);
    }
    float ss = f0 * f0 + f1 * f1 + f2 * f2 + f3 * f3;
    #pragma unroll
    for (int m = 1; m < 64; m <<= 1) ss += __shfl_xor(ss, m, 64);
    __shared__ float red[4];
    const int wave = threadIdx.x >> 6, lane = threadIdx.x & 63;
    if (lane == 0) red[wave] = ss;
    __syncthreads();
    float ms = (red[0] + red[1] + red[2] + red[3]) * (1.f / 1024.f);
    float rinv = rsqrtf(ms + 1e-6f);
    s16x4 ov;
    ov[0] = (short)f2bf(f0 * (scl[n * 1024 + base + 0] + 1.f) * rinv);
    ov[1] = (short)f2bf(f1 * (scl[n * 1024 + base + 1] + 1.f) * rinv);
    ov[2] = (short)f2bf(f2 * (scl[n * 1024 + base + 2] + 1.f) * rinv);
    ov[3] = (short)f2bf(f3 * (scl[n * 1024 + base + 3] + 1.f) * rinv);
    *(s16x4*)(orow + base) = ov;
}

// ---------------- fused dual transpose (w_qkv 1024x3072 + w_out 1024x1024) -----------
// grid (128, 32): bx < 96 -> w_qkv tile, else w_out tile. One launch instead of two.
__global__ __launch_bounds__(256) void transpose_both(const void* __restrict__ src_qkv,
                                                      u16* __restrict__ dst_qkv,
                                                      const void* __restrict__ src_out,
                                                      u16* __restrict__ dst_out,
                                                      const int* __restrict__ flag) {
    const int isf32 = *flag;
    __shared__ u16 t[32][33];
    const void* src; u16* dst; int C, c0;
    const int R = 1024;
    if (blockIdx.x < 96) { src = src_qkv; dst = dst_qkv; C = 3072; c0 = blockIdx.x * 32; }
    else                 { src = src_out; dst = dst_out; C = 1024; c0 = (blockIdx.x - 96) * 32; }
    const int r0 = blockIdx.y * 32;
    const int tx = threadIdx.x & 31, ty = threadIdx.x >> 5;
    #pragma unroll
    for (int i = 0; i < 4; ++i)
        t[ty + i * 8][tx] = f2bf(loadIn(src, (size_t)(r0 + ty + i * 8) * C + c0 + tx, isf32));
    __syncthreads();
    #pragma unroll
    for (int i = 0; i < 4; ++i)
        dst[(size_t)(c0 + ty + i * 8) * R + r0 + tx] = t[tx][ty + i * 8];
}

// ---------------- bf16 GEMM: C[M,N] = A[M,K] * BT[N,K]^T, 128x128 tile, BK=32 --------
// dbuf LDS + counted s_waitcnt vmcnt(4) (attn10's proven chunk flow). 4 loads/thr/chunk.
template <typename OutT>
__global__ __launch_bounds__(256) void gemm_bt(const u16* __restrict__ A,
                                               const u16* __restrict__ BT,
                                               OutT* __restrict__ C, int Nn, int K) {
    __shared__ u16 As[2][128 * 32];
    __shared__ u16 Bs[2][128 * 32];
    const int tid = threadIdx.x;
    const int wave = tid >> 6, lane = tid & 63;
    const int l15 = lane & 15, quad = lane >> 4;
    const int bm0 = blockIdx.y * 128, bn0 = blockIdx.x * 128;
    const int wr = wave >> 1, wc = wave & 1;
    f32x4 acc[4][4] = {};
    const int srow = lane >> 2;
    const int g = (lane & 3) ^ (srow & 3);

    auto stageg = [&](int ck, int slot) {
        const int bk = ck * 32;
        #pragma unroll
        for (int p = 0; p < 2; ++p) {
            const int rowl = p * 64 + wave * 16 + srow;
            const u16* ga = A + (size_t)(bm0 + rowl) * K + bk + g * 8;
            u16* la = As[slot] + (p * 64 + wave * 16) * 32;
            __builtin_amdgcn_global_load_lds((const AS1 void*)ga, (AS3 void*)la, 16, 0, 0);
            const u16* gb = BT + (size_t)(bn0 + rowl) * K + bk + g * 8;
            u16* lb = Bs[slot] + (p * 64 + wave * 16) * 32;
            __builtin_amdgcn_global_load_lds((const AS1 void*)gb, (AS3 void*)lb, 16, 0, 0);
        }
    };

    const int NC = K >> 5;
    stageg(0, 0);
    for (int j = 0; j < NC; ++j) {
        if (j > 0) __builtin_amdgcn_s_barrier();
        if (j < NC - 1) {
            stageg(j + 1, (j + 1) & 1);
            asm volatile("s_waitcnt vmcnt(4)" ::: "memory");
        } else {
            asm volatile("s_waitcnt vmcnt(0)" ::: "memory");
        }
        __builtin_amdgcn_sched_barrier(0);
        __builtin_amdgcn_s_barrier();

        const u16* Ac = As[j & 1];
        const u16* Bc = Bs[j & 1];
        s16x8 af[4], bfr[4];
        #pragma unroll
        for (int mt = 0; mt < 4; ++mt) {
            const int r = wr * 64 + mt * 16 + l15;
            af[mt] = *(const s16x8*)(Ac + r * 32 + ((quad ^ (r & 3)) << 3));
        }
        #pragma unroll
        for (int nt = 0; nt < 4; ++nt) {
            const int r = wc * 64 + nt * 16 + l15;
            bfr[nt] = *(const s16x8*)(Bc + r * 32 + ((quad ^ (r & 3)) << 3));
        }
        #pragma unroll
        for (int mt = 0; mt < 4; ++mt)
            #pragma unroll
            for (int nt = 0; nt < 4; ++nt)
                acc[mt][nt] = __builtin_amdgcn_mfma_f32_16x16x32_bf16(af[mt], bfr[nt], acc[mt][nt], 0, 0, 0);
    }
    #pragma unroll
    for (int mt = 0; mt < 4; ++mt)
        #pragma unroll
        for (int nt = 0; nt < 4; ++nt)
            #pragma unroll
            for (int r = 0; r < 4; ++r) {
                const int row = bm0 + wr * 64 + mt * 16 + quad * 4 + r;
                const int col = bn0 + wc * 64 + nt * 16 + l15;
                storeOut(C + (size_t)row * Nn + col, acc[mt][nt][r]);
            }
}

// ---------------- bf16 GEMM, 128x64 tile (2 blocks/CU for the narrow out-GEMM) -------
template <typename OutT>
__global__ __launch_bounds__(256) void gemm_bt64(const u16* __restrict__ A,
                                                 const u16* __restrict__ BT,
                                                 OutT* __restrict__ C, int Nn, int K) {
    __shared__ u16 As[2][128 * 32];
    __shared__ u16 Bs[2][64 * 32];
    const int tid = threadIdx.x;
    const int wave = tid >> 6, lane = tid & 63;
    const int l15 = lane & 15, quad = lane >> 4;
    const int bm0 = blockIdx.y * 128, bn0 = blockIdx.x * 64;
    const int wr = wave >> 1, wc = wave & 1;
    f32x4 acc[4][2] = {};
    const int srow = lane >> 2;
    const int g = (lane & 3) ^ (srow & 3);

    auto stageg = [&](int ck, int slot) {
        const int bk = ck * 32;
        #pragma unroll
        for (int p = 0; p < 2; ++p) {
            const int rowl = p * 64 + wave * 16 + srow;
            const u16* ga = A + (size_t)(bm0 + rowl) * K + bk + g * 8;
            u16* la = As[slot] + (p * 64 + wave * 16) * 32;
            __builtin_amdgcn_global_load_lds((const AS1 void*)ga, (AS3 void*)la, 16, 0, 0);
        }
        {
            const int rowl = wave * 16 + srow;
            const u16* gb = BT + (size_t)(bn0 + rowl) * K + bk + g * 8;
            u16* lb = Bs[slot] + (wave * 16) * 32;
            __builtin_amdgcn_global_load_lds((const AS1 void*)gb, (AS3 void*)lb, 16, 0, 0);
        }
    };

    const int NC = K >> 5;
    stageg(0, 0);
    for (int j = 0; j < NC; ++j) {
        if (j > 0) __builtin_amdgcn_s_barrier();
        if (j < NC - 1) {
            stageg(j + 1, (j + 1) & 1);
            asm volatile("s_waitcnt vmcnt(3)" ::: "memory");
        } else {
            asm volatile("s_waitcnt vmcnt(0)" ::: "memory");
        }
        __builtin_amdgcn_sched_barrier(0);
        __builtin_amdgcn_s_barrier();

        const u16* Ac = As[j & 1];
        const u16* Bc = Bs[j & 1];
        s16x8 af[4], bfr[2];
        #pragma unroll
        for (int mt = 0; mt < 4; ++mt) {
            const int r = wr * 64 + mt * 16 + l15;
            af[mt] = *(const s16x8*)(Ac + r * 32 + ((quad ^ (r & 3)) << 3));
        }
        #pragma unroll
        for (int nt = 0; nt < 2; ++nt) {
            const int r = wc * 32 + nt * 16 + l15;
            bfr[nt] = *(const s16x8*)(Bc + r * 32 + ((quad ^ (r & 3)) << 3));
        }
        #pragma unroll
        for (int mt = 0; mt < 4; ++mt)
            #pragma unroll
            for (int nt = 0; nt < 2; ++nt)
                acc[mt][nt] = __builtin_amdgcn_mfma_f32_16x16x32_bf16(af[mt], bfr[nt], acc[mt][nt], 0, 0, 0);
    }
    #pragma unroll
    for (int mt = 0; mt < 4; ++mt)
        #pragma unroll
        for (int nt = 0; nt < 2; ++nt)
            #pragma unroll
            for (int r = 0; r < 4; ++r) {
                const int row = bm0 + wr * 64 + mt * 16 + quad * 4 + r;
                const int col = bn0 + wc * 32 + nt * 16 + l15;
                storeOut(C + (size_t)row * Nn + col, acc[mt][nt][r]);
            }
}

// ---------------- fused per-head q/k RMS+RoPE + V transpose (v2: 4 tok/wave-iter) ----
// grid (32 l-tiles, 32 nh), 256 thr. v2 (G13): lane handles 4 contiguous e of ONE
// token; 16 lanes/token, 4 tokens/wave/iter, 4 iters. Loads/stores s16x4 (8B/lane);
// RMS reduce = 4-level shfl_xor(width 16); RoPE partner (e^32) = shfl_xor(8,16).
// Cross-lane ops per 16 tokens: 64 vs v1's 224. Trig count unchanged.
// q scaled by s^2/8 * log2(e) so attention softmax uses exp2 with fixed shift.
__global__ __launch_bounds__(256) void qkv_head(const u16* __restrict__ qkv,
                                                const void* __restrict__ pos,
                                                const void* __restrict__ qk_scale,
                                                u16* __restrict__ q_ws,
                                                u16* __restrict__ k_ws,
                                                u16* __restrict__ vtg,
                                                const int* __restrict__ flag) {
    const int isf32 = *flag;
    const int nh = blockIdx.y;
    const int n = nh >> 4, h = nh & 15;
    const int l0 = blockIdx.x * 64;
    const int tid = threadIdx.x;
    const int wave = tid >> 6, lane = tid & 63;
    const int tg = lane >> 4;        // token subgroup 0..3
    const int g  = lane & 15;        // e-group: this lane owns e = g*4 .. g*4+3

    // per-head constants
    const float qs = loadIn(qk_scale, h, isf32);
    const float s = __expf(0.5f * fminf(qs, 4.605170186f) - 1.039720771f);
    const float qmul = s * s * 0.125f * 1.44269504089f;
    // per-element rope constants (hoisted): e_i = g*4+i, j = e_i & 31,
    // freq_i = pi * exp(((j&15)*16 + h) * ln10/256). pj constant per lane.
    float freqv[4];
    #pragma unroll
    for (int i = 0; i < 4; ++i) {
        const int e = g * 4 + i;
        const float t = (float)(((e & 31) & 15) * 16 + h);
        freqv[i] = 3.14159265358979f * __expf(t * (2.302585093f / 256.f));
    }
    const int pj = (g >> 2) & 1;     // j>>4 for all 4 elems of this lane
    const float sgn = (g < 8) ? -1.f : 1.f;   // e<32: -sin ; e>=32: +sin

    #pragma unroll 2
    for (int it = 0; it < 4; ++it) {
        const int l = l0 + wave * 16 + it * 4 + tg;
        const int tok = n * 2048 + l;
        const u16* row = qkv + (size_t)tok * 3072;
        const s16x4 qv4 = *(const s16x4*)(row + h * 64 + g * 4);
        const s16x4 kv4 = *(const s16x4*)(row + 1024 + h * 64 + g * 4);
        float qv[4], kv[4];
        #pragma unroll
        for (int i = 0; i < 4; ++i) { qv[i] = bf2f((u16)qv4[i]); kv[i] = bf2f((u16)kv4[i]); }
        float q2 = qv[0] * qv[0] + qv[1] * qv[1] + qv[2] * qv[2] + qv[3] * qv[3];
        float k2 = kv[0] * kv[0] + kv[1] * kv[1] + kv[2] * kv[2] + kv[3] * kv[3];
        #pragma unroll
        for (int m = 1; m < 16; m <<= 1) { q2 += __shfl_xor(q2, m, 16); k2 += __shfl_xor(k2, m, 16); }
        const float qsc = rsqrtf(q2 * (1.f / 64.f) + 1e-6f) * qmul;
        const float ksc = rsqrtf(k2 * (1.f / 64.f) + 1e-6f);
        const float p = loadIn(pos, tok * 2 + pj, isf32);
        float qr[4], kr[4];
        #pragma unroll
        for (int i = 0; i < 4; ++i) {
            const float qn = qv[i] * qsc;
            const float kn = kv[i] * ksc;
            const float th = p * freqv[i];
            const float c = __cosf(th), sn = __sinf(th);
            const float pq = __shfl_xor(qn, 8, 16);   // partner e ^ 32
            const float pk = __shfl_xor(kn, 8, 16);
            qr[i] = qn * c + sgn * pq * sn;
            kr[i] = kn * c + sgn * pk * sn;
        }
        s16x4 qo, ko;
        #pragma unroll
        for (int i = 0; i < 4; ++i) { qo[i] = (short)f2bf(qr[i]); ko[i] = (short)f2bf(kr[i]); }
        const size_t oidx = ((size_t)nh * 2048 + l) * 64 + g * 4;
        *(s16x4*)(q_ws + oidx) = qo;
        *(s16x4*)(k_ws + oidx) = ko;
    }

    // V transpose: 64 l x 64 e tile -> vtg[nh][e][l]
    __shared__ u16 tbuf[64][65];
    const u16* vsrc = qkv + (size_t)(n * 2048 + l0) * 3072 + 2048 + h * 64;
    #pragma unroll
    for (int it = 0; it < 16; ++it) {
        const int idx = it * 256 + tid;
        const int r = idx >> 6, c = idx & 63;
        tbuf[r][c] = vsrc[(size_t)r * 3072 + c];
    }
    __syncthreads();
    u16* dst = vtg + (size_t)nh * 131072 + l0;
    #pragma unroll
    for (int it = 0; it < 16; ++it) {
        const int idx = it * 256 + tid;
        const int er = idx >> 6, lc = idx & 63;
        dst[(size_t)er * 2048 + lc] = tbuf[lc][er];
    }
}

// ---------------- flash attention v10: k-split 16-wave, 4 waves/SIMD (best: 47.1us) --
// 1024 thr (16 waves), q-tile 256, grid (8, 32) = 256 blocks = 1/CU.
// Wave = (wq = wave&7 -> q-rows wq*32, ks = wave>>3 -> kt-half). Each 256-key chunk's
// 8 kt split 4/4 between ks groups. Fixed-shift softmax (no running max) => partial
// (Oacc, lacc) combine by PURE ADD through LDS at the end. Chunked 256-key staging,
// dbuf 128 KB, counted vmcnt(4). s_setprio(1) around MFMA clusters.
__global__ __launch_bounds__(1024) void attn10(const u16* __restrict__ Q,
                                               const u16* __restrict__ K,
                                               const u16* __restrict__ Vtg,
                                               u16* __restrict__ O) {
    __shared__ u16 Ks[2][256 * 64];   // chunk rows x 64 e (128 B rows)
    __shared__ u16 Vt[2][64 * 256];   // 64 e-rows x chunk cols (512 B rows)
    const int nh = blockIdx.y;
    const int q0 = blockIdx.x * 256;
    const int tid = threadIdx.x;
    const int wave = tid >> 6, lane = tid & 63;
    const int wq = wave & 7, ks = wave >> 3;
    const int l31 = lane & 31, h = lane >> 5;
    const size_t hb = (size_t)nh * 2048 * 64;
    const u16* Vbase = Vtg + (size_t)nh * 131072;

    // Q fragments (B-operand of 32x32x16: col=q=l31, rows e=kd*16+h*8+0..7)
    s16x8 qf[4];
    #pragma unroll
    for (int kd = 0; kd < 4; ++kd)
        qf[kd] = *(const s16x8*)(Q + hb + (size_t)(q0 + wq * 32 + l31) * 64 + kd * 16 + h * 8);

    f32x16 Oacc[2] = {};
    float lacc = 0.f;

    // stage one 256-key chunk across 16 waves: K 32 KB (2 rounds of 128 rows) +
    // V 32 KB (2 rounds of 32 e-rows) = 4 global_load_lds per thread.
    auto stage = [&](int ch, int slot) {
        const int kb = ch * 256;
        #pragma unroll
        for (int r = 0; r < 2; ++r) {
            const int row = r * 128 + (tid >> 3);
            const int g = (tid & 7) ^ (row & 7);
            __builtin_amdgcn_global_load_lds(
                (const AS1 void*)(K + hb + (size_t)(kb + row) * 64 + g * 8),
                (AS3 void*)(Ks[slot] + (r * 128 + wave * 8) * 64), 16, 0, 0);
        }
        #pragma unroll
        for (int r = 0; r < 2; ++r) {
            const int er = r * 32 + (tid >> 5);
            const int g2 = (lane & 31) ^ (er & 7);
            __builtin_amdgcn_global_load_lds(
                (const AS1 void*)(Vbase + (size_t)er * 2048 + kb + g2 * 8),
                (AS3 void*)(Vt[slot] + (r * 32 + wave * 2) * 256), 16, 0, 0);
        }
    };

    stage(0, 0);

    for (int j = 0; j < 8; ++j) {
        // top barrier: all waves finished reading buf[(j+1)&1] (used by chunk j-1)
        if (j > 0) __builtin_amdgcn_s_barrier();
        if (j < 7) {
            stage(j + 1, (j + 1) & 1);
            // wait for chunk j's 4 loads (oldest); 4 newest (chunk j+1) stay in flight
            asm volatile("s_waitcnt vmcnt(4)" ::: "memory");
        } else {
            asm volatile("s_waitcnt vmcnt(0)" ::: "memory");
        }
        __builtin_amdgcn_sched_barrier(0);
        __builtin_amdgcn_s_barrier();   // all waves' chunk-j rows present in LDS

        const u16* Kt = Ks[j & 1];
        const u16* Vc = Vt[j & 1];

        #pragma unroll 2
        for (int t = 0; t < 4; ++t) {
            const int kt = ks * 4 + t;   // this wave-group's kt-half
            // ---- QK: S^T(32k x 32q) = K-slice * Q^T, contraction e=64 in 4 steps ----
            f32x16 S;
            #pragma unroll
            for (int jj = 0; jj < 16; ++jj) S[jj] = -15.f;
            const int kr = kt * 32 + l31;
            __builtin_amdgcn_s_setprio(1);
            #pragma unroll
            for (int kd = 0; kd < 4; ++kd) {
                const s16x8 kf = *(const s16x8*)(Kt + kr * 64 + ((((kd << 1) + h) ^ (kr & 7)) << 3));
                S = __builtin_amdgcn_mfma_f32_32x32x16_bf16(kf, qf[kd], S, 0, 0, 0);
            }
            __builtin_amdgcn_s_setprio(0);
            // ---- softmax: exp2 (shift -15 in acc init), row-sum partial ----
            float e[16];
            #pragma unroll
            for (int jj = 0; jj < 16; ++jj) e[jj] = fexp2(S[jj]);
            float rs = 0.f;
            #pragma unroll
            for (int jj = 0; jj < 16; ++jj) rs += e[jj];
            lacc += rs;
            // ---- pack P to bf16 pairs + half-swap into PV A-fragments ----
            u32 c[8];
            #pragma unroll
            for (int jj = 0; jj < 8; ++jj)
                asm("v_cvt_pk_bf16_f32 %0, %1, %2" : "=v"(c[jj]) : "v"(e[2 * jj]), "v"(e[2 * jj + 1]));
            plswap(c[0], c[2]);
            plswap(c[1], c[3]);
            plswap(c[4], c[6]);
            plswap(c[5], c[7]);
            union { u32 u[4]; s16x8 v; } pfa, pfb;
            pfa.u[0] = c[0]; pfa.u[1] = c[1]; pfa.u[2] = c[2]; pfa.u[3] = c[3];
            pfb.u[0] = c[4]; pfb.u[1] = c[5]; pfb.u[2] = c[6]; pfb.u[3] = c[7];
            // ---- PV: Oacc(32q x 32e per et) += P(32q x 32k) * V(32k x 32e) ----
            __builtin_amdgcn_s_setprio(1);
            #pragma unroll
            for (int et = 0; et < 2; ++et) {
                const int er = et * 32 + l31;
                #pragma unroll
                for (int kdp = 0; kdp < 2; ++kdp) {
                    const int ch = kt * 4 + kdp * 2 + h;
                    const s16x8 vf = *(const s16x8*)(Vc + er * 256 + ((ch ^ (er & 7)) << 3));
                    Oacc[et] = __builtin_amdgcn_mfma_f32_32x32x16_bf16(kdp ? pfb.v : pfa.v, vf, Oacc[et], 0, 0, 0);
                }
            }
            __builtin_amdgcn_s_setprio(0);
        }
    }

    // ---- combine the two kt-half groups: pure add (fixed-shift softmax, no max) ----
    __syncthreads();   // all waves done reading Ks/Vt -> safe to overlay
    float (*Osh)[512] = (float(*)[512]) & Ks[0][0];   // 32 x 512 f32 = 64 KB
    float* Lsh = (float*)&Vt[0][0];                   // 512 f32
    if (ks == 1) {
        #pragma unroll
        for (int et = 0; et < 2; ++et)
            #pragma unroll
            for (int r = 0; r < 16; ++r)
                Osh[et * 16 + r][wq * 64 + lane] = Oacc[et][r];
        Lsh[wq * 64 + lane] = lacc;
    }
    __syncthreads();
    if (ks == 0) {
        #pragma unroll
        for (int et = 0; et < 2; ++et)
            #pragma unroll
            for (int r = 0; r < 16; ++r)
                Oacc[et][r] += Osh[et * 16 + r][wq * 64 + lane];
        lacc += Lsh[wq * 64 + lane];

        // ---- epilogue: combine row-sums across lane halves, normalize, store ----
        lacc += __shfl_xor(lacc, 32, 64);
        const float linv_l = 1.f / lacc;   // lane l31 holds 1/l for q = l31
        const int n = nh >> 4, hh = nh & 15;
        #pragma unroll
        for (int r = 0; r < 16; ++r) {
            const int ql = (r & 3) + 8 * (r >> 2) + 4 * h;   // q-row of D-reg r
            const float linv = __shfl(linv_l, ql, 64);
            const int qrow = q0 + wq * 32 + ql;
            #pragma unroll
            for (int et = 0; et < 2; ++et)
                O[((size_t)n * 2048 + qrow) * 1024 + hh * 64 + et * 32 + l31] = f2bf(Oacc[et][r] * linv);
        }
    }
}

// ---------------- launch --------------------------------------------------------------
extern "C" void kernel_launch(void* const* d_in, const int* in_sizes, int n_in,
                              void* d_out, int out_size, void* d_ws, size_t ws_size,
                              hipStream_t stream) {
    const void* x        = d_in[0];
    const void* pos      = d_in[1];
    const void* cond     = d_in[2];
    const void* w_cond   = d_in[3];
    const void* w_qkv    = d_in[4];
    const void* qk_scale = d_in[5];
    const void* w_out    = d_in[6];

    char* ws = (char*)d_ws;
    constexpr size_t OFS_SCALE = 0;
    constexpr size_t OFS_FLAG  = 8192;
    constexpr size_t OFS_XN    = 16384;
    constexpr size_t OFS_WQKVT = OFS_XN    + 8388608;
    constexpr size_t OFS_WOUTT = OFS_WQKVT + 6291456;
    constexpr size_t OFS_QKV   = OFS_WOUTT + 2097152;
    constexpr size_t OFS_Q     = OFS_QKV   + 25165824;
    constexpr size_t OFS_K     = OFS_Q     + 8388608;
    constexpr size_t OFS_VT    = OFS_K     + 8388608;
    constexpr size_t OFS_O     = OFS_VT    + 8388608;

    float* scale = (float*)(ws + OFS_SCALE);
    int*   flag  = (int*)(ws + OFS_FLAG);
    u16* xn    = (u16*)(ws + OFS_XN);
    u16* wqkvT = (u16*)(ws + OFS_WQKVT);
    u16* woutT = (u16*)(ws + OFS_WOUTT);
    u16* qkv   = (u16*)(ws + OFS_QKV);
    u16* qws   = (u16*)(ws + OFS_Q);
    u16* kws   = (u16*)(ws + OFS_K);
    u16* vtg   = (u16*)(ws + OFS_VT);
    u16* ows   = (u16*)(ws + OFS_O);

    detect_dtype<<<dim3(1), 256, 0, stream>>>((const u16*)x, flag);
    hipMemsetAsync(scale, 0, 2 * 1024 * sizeof(float), stream);
    cond_gemv<<<dim3(4, 2, 16), 256, 0, stream>>>(cond, w_cond, scale, flag);
    rmsnorm_x<<<dim3(4096), 256, 0, stream>>>(x, scale, xn, flag);
    transpose_both<<<dim3(128, 32), 256, 0, stream>>>(w_qkv, wqkvT, w_out, woutT, flag);
    gemm_bt<u16><<<dim3(24, 32), 256, 0, stream>>>(xn, wqkvT, qkv, 3072, 1024);
    qkv_head<<<dim3(32, 32), 256, 0, stream>>>(qkv, pos, qk_scale, qws, kws, vtg, flag);
    attn10<<<dim3(8, 32), 1024, 0, stream>>>(qws, kws, vtg, ows);
    gemm_bt64<float><<<dim3(16, 32), 256, 0, stream>>>(ows, woutT, (float*)d_out, 1024, 1024);
}

// Round 12
// 209.499 us; speedup vs baseline: 1.1527x; 1.0544x over previous
//
#include <hip/hip_runtime.h>

typedef unsigned short u16;
typedef unsigned int u32;
typedef short s16x8 __attribute__((ext_vector_type(8)));
typedef short s16x4 __attribute__((ext_vector_type(4)));
typedef float f32x4 __attribute__((ext_vector_type(4)));
typedef float f32x16 __attribute__((ext_vector_type(16)));

#define AS1 __attribute__((address_space(1)))
#define AS3 __attribute__((address_space(3)))

__device__ __forceinline__ float bf2f(u16 u) {
    union { unsigned int i; float f; } x; x.i = ((unsigned int)u) << 16; return x.f;
}
__device__ __forceinline__ u16 f2bf(float f) {
    union { float f; unsigned int i; } x; x.f = f;
    unsigned int r = (x.i + 0x7FFFu + ((x.i >> 16) & 1u)) >> 16;
    return (u16)r;
}
__device__ __forceinline__ void storeOut(u16* p, float v) { *p = f2bf(v); }
__device__ __forceinline__ void storeOut(float* p, float v) { *p = v; }
__device__ __forceinline__ float loadIn(const void* p, size_t i, int isf32) {
    return isf32 ? ((const float*)p)[i] : bf2f(((const u16*)p)[i]);
}
__device__ __forceinline__ float fexp2(float x) {
#if __has_builtin(__builtin_amdgcn_exp2f)
    return __builtin_amdgcn_exp2f(x);
#else
    return exp2f(x);
#endif
}
// exchange upper half-lanes of a with lower half-lanes of b (v_permlane32_swap_b32)
__device__ __forceinline__ void plswap(u32& a, u32& b) {
#if __has_builtin(__builtin_amdgcn_permlane32_swap)
    const auto r = __builtin_amdgcn_permlane32_swap(a, b, false, false);
    a = (u32)r[0]; b = (u32)r[1];
#else
    asm("v_permlane32_swap_b32 %0, %1" : "+v"(a), "+v"(b));
#endif
}

// ---------------- runtime dtype detector ---------------------------------------------
__global__ __launch_bounds__(256) void detect_dtype(const u16* __restrict__ x,
                                                    int* __restrict__ flag) {
    __shared__ int cnt[4];
    const int tid = threadIdx.x;
    int c = 0;
    #pragma unroll
    for (int i = 0; i < 4; ++i) {
        const u16 u = x[tid * 4 + i];
        const int e = (u >> 7) & 0xFF;
        c += (e >= 101 && e <= 135) ? 1 : 0;
    }
    #pragma unroll
    for (int m = 1; m < 64; m <<= 1) c += __shfl_xor(c, m, 64);
    if ((tid & 63) == 0) cnt[tid >> 6] = c;
    __syncthreads();
    if (tid == 0) {
        const int t = cnt[0] + cnt[1] + cnt[2] + cnt[3];
        *flag = (t < 800) ? 1 : 0;   // 1 = inputs are float32
    }
}

// ---------------- cond @ w_cond (split-K GEMV, atomicAdd into zeroed f32 ws) ----------
__global__ __launch_bounds__(256) void cond_gemv(const void* __restrict__ cond,
                                                 const void* __restrict__ w,
                                                 float* __restrict__ out,
                                                 const int* __restrict__ flag) {
    const int isf32 = *flag;
    const int d  = blockIdx.x * 256 + threadIdx.x;
    const int n  = blockIdx.y;
    const int k0 = blockIdx.z * 64;
    float acc = 0.f;
    #pragma unroll 8
    for (int k = 0; k < 64; ++k)
        acc += loadIn(cond, n * 1024 + k0 + k, isf32) *
               loadIn(w, (size_t)(k0 + k) * 1024 + d, isf32);
    atomicAdd(out + n * 1024 + d, acc);
}

// ---------------- RMS norm of x with scale = (cond@w_cond + 1) -----------------------
__global__ __launch_bounds__(256) void rmsnorm_x(const void* __restrict__ x,
                                                 const float* __restrict__ scl,
                                                 u16* __restrict__ xn,
                                                 const int* __restrict__ flag) {
    const int isf32 = *flag;
    const int tok = blockIdx.x;
    const int n = tok >> 11;
    u16* orow = xn + (size_t)tok * 1024;
    const int base = threadIdx.x * 4;
    float f0, f1, f2, f3;
    if (isf32) {
        const float4 v = *(const float4*)((const float*)x + (size_t)tok * 1024 + base);
        f0 = v.x; f1 = v.y; f2 = v.z; f3 = v.w;
    } else {
        s16x4 uv = *(const s16x4*)((const u16*)x + (size_t)tok * 1024 + base);
        f0 = bf2f((u16)uv[0]); f1 = bf2f((u16)uv[1]); f2 = bf2f((u16)uv[2]); f3 = bf2f((u16)uv[3]);
    }
    float ss = f0 * f0 + f1 * f1 + f2 * f2 + f3 * f3;
    #pragma unroll
    for (int m = 1; m < 64; m <<= 1) ss += __shfl_xor(ss, m, 64);
    __shared__ float red[4];
    const int wave = threadIdx.x >> 6, lane = threadIdx.x & 63;
    if (lane == 0) red[wave] = ss;
    __syncthreads();
    float ms = (red[0] + red[1] + red[2] + red[3]) * (1.f / 1024.f);
    float rinv = rsqrtf(ms + 1e-6f);
    s16x4 ov;
    ov[0] = (short)f2bf(f0 * (scl[n * 1024 + base + 0] + 1.f) * rinv);
    ov[1] = (short)f2bf(f1 * (scl[n * 1024 + base + 1] + 1.f) * rinv);
    ov[2] = (short)f2bf(f2 * (scl[n * 1024 + base + 2] + 1.f) * rinv);
    ov[3] = (short)f2bf(f3 * (scl[n * 1024 + base + 3] + 1.f) * rinv);
    *(s16x4*)(orow + base) = ov;
}

// ---------------- fused dual transpose (w_qkv 1024x3072 + w_out 1024x1024) -----------
// grid (128, 32): bx < 96 -> w_qkv tile, else w_out tile. One launch instead of two.
__global__ __launch_bounds__(256) void transpose_both(const void* __restrict__ src_qkv,
                                                      u16* __restrict__ dst_qkv,
                                                      const void* __restrict__ src_out,
                                                      u16* __restrict__ dst_out,
                                                      const int* __restrict__ flag) {
    const int isf32 = *flag;
    __shared__ u16 t[32][33];
    const void* src; u16* dst; int C, c0;
    const int R = 1024;
    if (blockIdx.x < 96) { src = src_qkv; dst = dst_qkv; C = 3072; c0 = blockIdx.x * 32; }
    else                 { src = src_out; dst = dst_out; C = 1024; c0 = (blockIdx.x - 96) * 32; }
    const int r0 = blockIdx.y * 32;
    const int tx = threadIdx.x & 31, ty = threadIdx.x >> 5;
    #pragma unroll
    for (int i = 0; i < 4; ++i)
        t[ty + i * 8][tx] = f2bf(loadIn(src, (size_t)(r0 + ty + i * 8) * C + c0 + tx, isf32));
    __syncthreads();
    #pragma unroll
    for (int i = 0; i < 4; ++i)
        dst[(size_t)(c0 + ty + i * 8) * R + r0 + tx] = t[tx][ty + i * 8];
}

// ---------------- fused qkv GEMM + per-head RMS/RoPE/V-transpose epilogue ------------
// C[M=4096, N=3072] = xn[4096,1024] * wqkvT[3072,1024]^T, 128x128 tile, BK=32,
// dbuf LDS + counted vmcnt(4) (proven gemm_bt flow). The epilogue consumes acc
// DIRECTLY (qkv never touches HBM):
//   bx<8  (q cols): per-row RMS (4 sq + 4-level shfl_xor width 16) -> *qmul -> RoPE
//                   (partner e^32 = acc[mt][nt^2][rr], in-register) -> qws[nh][l][e]
//   bx<16 (k cols): same with ksc (no qmul) -> kws
//   bx>=16 (v):     LDS transpose (reuse staging buffer after barrier) -> vtg[nh][e][l]
// Wave layout fact used: acc row = bm0+wr*64+mt*16+quad*4+rr (= token), col =
// bn0+wc*64+nt*16+l15 -> one wave's 64 cols = exactly one head's e-span.
// freq: t = l15*16+hh (per-lane const); pj = nt&1; sign: nt<2 -> -sin, else +sin.
__global__ __launch_bounds__(256) void gemm_qkv(const u16* __restrict__ A,
                                                const u16* __restrict__ BT,
                                                const void* __restrict__ pos,
                                                const void* __restrict__ qk_scale,
                                                u16* __restrict__ qws,
                                                u16* __restrict__ kws,
                                                u16* __restrict__ vtg,
                                                const int* __restrict__ flag) {
    constexpr int K = 1024;
    __shared__ u16 sbuf[128 * 136];            // 34 KB; staging uses first 32 KB
    u16* As = sbuf;                            // [2][128*32]
    u16* Bs = sbuf + 8192;                     // [2][128*32]
    const int tid = threadIdx.x;
    const int wave = tid >> 6, lane = tid & 63;
    const int l15 = lane & 15, quad = lane >> 4;
    const int bm0 = blockIdx.y * 128, bn0 = blockIdx.x * 128;
    const int wr = wave >> 1, wc = wave & 1;
    f32x4 acc[4][4] = {};
    const int srow = lane >> 2;
    const int g = (lane & 3) ^ (srow & 3);

    auto stageg = [&](int ck, int slot) {
        const int bk = ck * 32;
        #pragma unroll
        for (int p = 0; p < 2; ++p) {
            const int rowl = p * 64 + wave * 16 + srow;
            const u16* ga = A + (size_t)(bm0 + rowl) * K + bk + g * 8;
            u16* la = As + slot * 4096 + (p * 64 + wave * 16) * 32;
            __builtin_amdgcn_global_load_lds((const AS1 void*)ga, (AS3 void*)la, 16, 0, 0);
            const u16* gb = BT + (size_t)(bn0 + rowl) * K + bk + g * 8;
            u16* lb = Bs + slot * 4096 + (p * 64 + wave * 16) * 32;
            __builtin_amdgcn_global_load_lds((const AS1 void*)gb, (AS3 void*)lb, 16, 0, 0);
        }
    };

    const int NC = K >> 5;
    stageg(0, 0);
    for (int j = 0; j < NC; ++j) {
        if (j > 0) __builtin_amdgcn_s_barrier();
        if (j < NC - 1) {
            stageg(j + 1, (j + 1) & 1);
            asm volatile("s_waitcnt vmcnt(4)" ::: "memory");
        } else {
            asm volatile("s_waitcnt vmcnt(0)" ::: "memory");
        }
        __builtin_amdgcn_sched_barrier(0);
        __builtin_amdgcn_s_barrier();

        const u16* Ac = As + (j & 1) * 4096;
        const u16* Bc = Bs + (j & 1) * 4096;
        s16x8 af[4], bfr[4];
        #pragma unroll
        for (int mt = 0; mt < 4; ++mt) {
            const int r = wr * 64 + mt * 16 + l15;
            af[mt] = *(const s16x8*)(Ac + r * 32 + ((quad ^ (r & 3)) << 3));
        }
        #pragma unroll
        for (int nt = 0; nt < 4; ++nt) {
            const int r = wc * 64 + nt * 16 + l15;
            bfr[nt] = *(const s16x8*)(Bc + r * 32 + ((quad ^ (r & 3)) << 3));
        }
        #pragma unroll
        for (int mt = 0; mt < 4; ++mt)
            #pragma unroll
            for (int nt = 0; nt < 4; ++nt)
                acc[mt][nt] = __builtin_amdgcn_mfma_f32_16x16x32_bf16(af[mt], bfr[nt], acc[mt][nt], 0, 0, 0);
    }

    // ---------------- fused epilogue ----------------
    const int isf32 = *flag;
    const int bx = blockIdx.x;
    const int rowbase = bm0 + wr * 64;
    const int n = rowbase >> 11;               // batch (64-row band never crosses 2048)
    const int colw = bn0 + wc * 64;            // this wave's 64-col head span

    if (bx < 16) {
        // ---- q (bx<8) or k: per-row RMS + RoPE, write to head-major layout ----
        const int isq = (bx < 8);
        const int hh = (colw >> 6) & 15;
        float mul = 1.f;
        if (isq) {
            const float qs = loadIn(qk_scale, hh, isf32);
            const float s = __expf(0.5f * fminf(qs, 4.605170186f) - 1.039720771f);
            mul = s * s * 0.125f * 1.44269504089f;
        }
        const float t = (float)(l15 * 16 + hh);
        const float freq = 3.14159265358979f * __expf(t * (2.302585093f / 256.f));
        u16* dstb = (isq ? qws : kws) + (size_t)(n * 16 + hh) * 2048 * 64;
        #pragma unroll
        for (int mt = 0; mt < 4; ++mt)
            #pragma unroll
            for (int rr = 0; rr < 4; ++rr) {
                const int row = rowbase + mt * 16 + quad * 4 + rr;   // global token
                const int l = row & 2047;
                float s2 = acc[mt][0][rr] * acc[mt][0][rr] + acc[mt][1][rr] * acc[mt][1][rr]
                         + acc[mt][2][rr] * acc[mt][2][rr] + acc[mt][3][rr] * acc[mt][3][rr];
                #pragma unroll
                for (int m = 1; m < 16; m <<= 1) s2 += __shfl_xor(s2, m, 16);
                const float sc = rsqrtf(s2 * (1.f / 64.f) + 1e-6f) * mul;
                const float p0 = loadIn(pos, (size_t)row * 2 + 0, isf32);
                const float p1 = loadIn(pos, (size_t)row * 2 + 1, isf32);
                const float c0 = __cosf(p0 * freq), sn0 = __sinf(p0 * freq);
                const float c1 = __cosf(p1 * freq), sn1 = __sinf(p1 * freq);
                const float a0 = acc[mt][0][rr] * sc, a1 = acc[mt][1][rr] * sc;
                const float a2 = acc[mt][2][rr] * sc, a3 = acc[mt][3][rr] * sc;
                u16* d = dstb + (size_t)l * 64 + l15;
                d[0]  = f2bf(a0 * c0 - a2 * sn0);    // e = l15      (pj=0, -sin)
                d[16] = f2bf(a1 * c1 - a3 * sn1);    // e = 16+l15   (pj=1, -sin)
                d[32] = f2bf(a2 * c0 + a0 * sn0);    // e = 32+l15   (pj=0, +sin)
                d[48] = f2bf(a3 * c1 + a1 * sn1);    // e = 48+l15   (pj=1, +sin)
            }
    } else {
        // ---- v: transpose via LDS (reuse staging buffer), write vtg[nh][e][l] ----
        __syncthreads();                       // all waves done with staging LDS
        #pragma unroll
        for (int mt = 0; mt < 4; ++mt)
            #pragma unroll
            for (int nt = 0; nt < 4; ++nt)
                #pragma unroll
                for (int rr = 0; rr < 4; ++rr)
                    sbuf[(wc * 64 + nt * 16 + l15) * 136 + (wr * 64 + mt * 16 + quad * 4 + rr)]
                        = f2bf(acc[mt][nt][rr]);
        __syncthreads();
        const int ec = tid >> 1, half = tid & 1;           // tile col 0..127, row half
        const int vcol = bn0 + ec - 2048;                  // v-dim global col
        const int hh = vcol >> 6, e = vcol & 63;
        const int lbase = (bm0 & 2047) + half * 64;
        u16* d = vtg + ((size_t)((bm0 >> 11) * 16 + hh) * 64 + e) * 2048 + lbase;
        #pragma unroll
        for (int i = 0; i < 8; ++i)
            *(s16x8*)(d + i * 8) = *(const s16x8*)(sbuf + ec * 136 + half * 64 + i * 8);
    }
}

// ---------------- bf16 GEMM, 128x64 tile (2 blocks/CU for the narrow out-GEMM) -------
template <typename OutT>
__global__ __launch_bounds__(256) void gemm_bt64(const u16* __restrict__ A,
                                                 const u16* __restrict__ BT,
                                                 OutT* __restrict__ C, int Nn, int K) {
    __shared__ u16 As[2][128 * 32];
    __shared__ u16 Bs[2][64 * 32];
    const int tid = threadIdx.x;
    const int wave = tid >> 6, lane = tid & 63;
    const int l15 = lane & 15, quad = lane >> 4;
    const int bm0 = blockIdx.y * 128, bn0 = blockIdx.x * 64;
    const int wr = wave >> 1, wc = wave & 1;
    f32x4 acc[4][2] = {};
    const int srow = lane >> 2;
    const int g = (lane & 3) ^ (srow & 3);

    auto stageg = [&](int ck, int slot) {
        const int bk = ck * 32;
        #pragma unroll
        for (int p = 0; p < 2; ++p) {
            const int rowl = p * 64 + wave * 16 + srow;
            const u16* ga = A + (size_t)(bm0 + rowl) * K + bk + g * 8;
            u16* la = As[slot] + (p * 64 + wave * 16) * 32;
            __builtin_amdgcn_global_load_lds((const AS1 void*)ga, (AS3 void*)la, 16, 0, 0);
        }
        {
            const int rowl = wave * 16 + srow;
            const u16* gb = BT + (size_t)(bn0 + rowl) * K + bk + g * 8;
            u16* lb = Bs[slot] + (wave * 16) * 32;
            __builtin_amdgcn_global_load_lds((const AS1 void*)gb, (AS3 void*)lb, 16, 0, 0);
        }
    };

    const int NC = K >> 5;
    stageg(0, 0);
    for (int j = 0; j < NC; ++j) {
        if (j > 0) __builtin_amdgcn_s_barrier();
        if (j < NC - 1) {
            stageg(j + 1, (j + 1) & 1);
            asm volatile("s_waitcnt vmcnt(3)" ::: "memory");
        } else {
            asm volatile("s_waitcnt vmcnt(0)" ::: "memory");
        }
        __builtin_amdgcn_sched_barrier(0);
        __builtin_amdgcn_s_barrier();

        const u16* Ac = As[j & 1];
        const u16* Bc = Bs[j & 1];
        s16x8 af[4], bfr[2];
        #pragma unroll
        for (int mt = 0; mt < 4; ++mt) {
            const int r = wr * 64 + mt * 16 + l15;
            af[mt] = *(const s16x8*)(Ac + r * 32 + ((quad ^ (r & 3)) << 3));
        }
        #pragma unroll
        for (int nt = 0; nt < 2; ++nt) {
            const int r = wc * 32 + nt * 16 + l15;
            bfr[nt] = *(const s16x8*)(Bc + r * 32 + ((quad ^ (r & 3)) << 3));
        }
        #pragma unroll
        for (int mt = 0; mt < 4; ++mt)
            #pragma unroll
            for (int nt = 0; nt < 2; ++nt)
                acc[mt][nt] = __builtin_amdgcn_mfma_f32_16x16x32_bf16(af[mt], bfr[nt], acc[mt][nt], 0, 0, 0);
    }
    #pragma unroll
    for (int mt = 0; mt < 4; ++mt)
        #pragma unroll
        for (int nt = 0; nt < 2; ++nt)
            #pragma unroll
            for (int r = 0; r < 4; ++r) {
                const int row = bm0 + wr * 64 + mt * 16 + quad * 4 + r;
                const int col = bn0 + wc * 32 + nt * 16 + l15;
                storeOut(C + (size_t)row * Nn + col, acc[mt][nt][r]);
            }
}

// ---------------- flash attention v10: k-split 16-wave, 4 waves/SIMD (proven) --------
// 1024 thr (16 waves), q-tile 256, grid (8, 32) = 256 blocks = 1/CU.
// Wave = (wq = wave&7 -> q-rows wq*32, ks = wave>>3 -> kt-half). Each 256-key chunk's
// 8 kt split 4/4 between ks groups. Fixed-shift softmax (no running max) => partial
// (Oacc, lacc) combine by PURE ADD through LDS at the end. Chunked 256-key staging,
// dbuf 128 KB, counted vmcnt(4). s_setprio(1) around MFMA clusters.
__global__ __launch_bounds__(1024) void attn10(const u16* __restrict__ Q,
                                               const u16* __restrict__ K,
                                               const u16* __restrict__ Vtg,
                                               u16* __restrict__ O) {
    __shared__ u16 Ks[2][256 * 64];   // chunk rows x 64 e (128 B rows)
    __shared__ u16 Vt[2][64 * 256];   // 64 e-rows x chunk cols (512 B rows)
    const int nh = blockIdx.y;
    const int q0 = blockIdx.x * 256;
    const int tid = threadIdx.x;
    const int wave = tid >> 6, lane = tid & 63;
    const int wq = wave & 7, ks = wave >> 3;
    const int l31 = lane & 31, h = lane >> 5;
    const size_t hb = (size_t)nh * 2048 * 64;
    const u16* Vbase = Vtg + (size_t)nh * 131072;

    // Q fragments (B-operand of 32x32x16: col=q=l31, rows e=kd*16+h*8+0..7)
    s16x8 qf[4];
    #pragma unroll
    for (int kd = 0; kd < 4; ++kd)
        qf[kd] = *(const s16x8*)(Q + hb + (size_t)(q0 + wq * 32 + l31) * 64 + kd * 16 + h * 8);

    f32x16 Oacc[2] = {};
    float lacc = 0.f;

    // stage one 256-key chunk across 16 waves: K 32 KB (2 rounds of 128 rows) +
    // V 32 KB (2 rounds of 32 e-rows) = 4 global_load_lds per thread.
    auto stage = [&](int ch, int slot) {
        const int kb = ch * 256;
        #pragma unroll
        for (int r = 0; r < 2; ++r) {
            const int row = r * 128 + (tid >> 3);
            const int g = (tid & 7) ^ (row & 7);
            __builtin_amdgcn_global_load_lds(
                (const AS1 void*)(K + hb + (size_t)(kb + row) * 64 + g * 8),
                (AS3 void*)(Ks[slot] + (r * 128 + wave * 8) * 64), 16, 0, 0);
        }
        #pragma unroll
        for (int r = 0; r < 2; ++r) {
            const int er = r * 32 + (tid >> 5);
            const int g2 = (lane & 31) ^ (er & 7);
            __builtin_amdgcn_global_load_lds(
                (const AS1 void*)(Vbase + (size_t)er * 2048 + kb + g2 * 8),
                (AS3 void*)(Vt[slot] + (r * 32 + wave * 2) * 256), 16, 0, 0);
        }
    };

    stage(0, 0);

    for (int j = 0; j < 8; ++j) {
        // top barrier: all waves finished reading buf[(j+1)&1] (used by chunk j-1)
        if (j > 0) __builtin_amdgcn_s_barrier();
        if (j < 7) {
            stage(j + 1, (j + 1) & 1);
            // wait for chunk j's 4 loads (oldest); 4 newest (chunk j+1) stay in flight
            asm volatile("s_waitcnt vmcnt(4)" ::: "memory");
        } else {
            asm volatile("s_waitcnt vmcnt(0)" ::: "memory");
        }
        __builtin_amdgcn_sched_barrier(0);
        __builtin_amdgcn_s_barrier();   // all waves' chunk-j rows present in LDS

        const u16* Kt = Ks[j & 1];
        const u16* Vc = Vt[j & 1];

        #pragma unroll 2
        for (int t = 0; t < 4; ++t) {
            const int kt = ks * 4 + t;   // this wave-group's kt-half
            // ---- QK: S^T(32k x 32q) = K-slice * Q^T, contraction e=64 in 4 steps ----
            f32x16 S;
            #pragma unroll
            for (int jj = 0; jj < 16; ++jj) S[jj] = -15.f;
            const int kr = kt * 32 + l31;
            __builtin_amdgcn_s_setprio(1);
            #pragma unroll
            for (int kd = 0; kd < 4; ++kd) {
                const s16x8 kf = *(const s16x8*)(Kt + kr * 64 + ((((kd << 1) + h) ^ (kr & 7)) << 3));
                S = __builtin_amdgcn_mfma_f32_32x32x16_bf16(kf, qf[kd], S, 0, 0, 0);
            }
            __builtin_amdgcn_s_setprio(0);
            // ---- softmax: exp2 (shift -15 in acc init), row-sum partial ----
            float e[16];
            #pragma unroll
            for (int jj = 0; jj < 16; ++jj) e[jj] = fexp2(S[jj]);
            float rs = 0.f;
            #pragma unroll
            for (int jj = 0; jj < 16; ++jj) rs += e[jj];
            lacc += rs;
            // ---- pack P to bf16 pairs + half-swap into PV A-fragments ----
            u32 c[8];
            #pragma unroll
            for (int jj = 0; jj < 8; ++jj)
                asm("v_cvt_pk_bf16_f32 %0, %1, %2" : "=v"(c[jj]) : "v"(e[2 * jj]), "v"(e[2 * jj + 1]));
            plswap(c[0], c[2]);
            plswap(c[1], c[3]);
            plswap(c[4], c[6]);
            plswap(c[5], c[7]);
            union { u32 u[4]; s16x8 v; } pfa, pfb;
            pfa.u[0] = c[0]; pfa.u[1] = c[1]; pfa.u[2] = c[2]; pfa.u[3] = c[3];
            pfb.u[0] = c[4]; pfb.u[1] = c[5]; pfb.u[2] = c[6]; pfb.u[3] = c[7];
            // ---- PV: Oacc(32q x 32e per et) += P(32q x 32k) * V(32k x 32e) ----
            __builtin_amdgcn_s_setprio(1);
            #pragma unroll
            for (int et = 0; et < 2; ++et) {
                const int er = et * 32 + l31;
                #pragma unroll
                for (int kdp = 0; kdp < 2; ++kdp) {
                    const int ch = kt * 4 + kdp * 2 + h;
                    const s16x8 vf = *(const s16x8*)(Vc + er * 256 + ((ch ^ (er & 7)) << 3));
                    Oacc[et] = __builtin_amdgcn_mfma_f32_32x32x16_bf16(kdp ? pfb.v : pfa.v, vf, Oacc[et], 0, 0, 0);
                }
            }
            __builtin_amdgcn_s_setprio(0);
        }
    }

    // ---- combine the two kt-half groups: pure add (fixed-shift softmax, no max) ----
    __syncthreads();   // all waves done reading Ks/Vt -> safe to overlay
    float (*Osh)[512] = (float(*)[512]) & Ks[0][0];   // 32 x 512 f32 = 64 KB
    float* Lsh = (float*)&Vt[0][0];                   // 512 f32
    if (ks == 1) {
        #pragma unroll
        for (int et = 0; et < 2; ++et)
            #pragma unroll
            for (int r = 0; r < 16; ++r)
                Osh[et * 16 + r][wq * 64 + lane] = Oacc[et][r];
        Lsh[wq * 64 + lane] = lacc;
    }
    __syncthreads();
    if (ks == 0) {
        #pragma unroll
        for (int et = 0; et < 2; ++et)
            #pragma unroll
            for (int r = 0; r < 16; ++r)
                Oacc[et][r] += Osh[et * 16 + r][wq * 64 + lane];
        lacc += Lsh[wq * 64 + lane];

        // ---- epilogue: combine row-sums across lane halves, normalize, store ----
        lacc += __shfl_xor(lacc, 32, 64);
        const float linv_l = 1.f / lacc;   // lane l31 holds 1/l for q = l31
        const int n = nh >> 4, hh = nh & 15;
        #pragma unroll
        for (int r = 0; r < 16; ++r) {
            const int ql = (r & 3) + 8 * (r >> 2) + 4 * h;   // q-row of D-reg r
            const float linv = __shfl(linv_l, ql, 64);
            const int qrow = q0 + wq * 32 + ql;
            #pragma unroll
            for (int et = 0; et < 2; ++et)
                O[((size_t)n * 2048 + qrow) * 1024 + hh * 64 + et * 32 + l31] = f2bf(Oacc[et][r] * linv);
        }
    }
}

// ---------------- launch --------------------------------------------------------------
extern "C" void kernel_launch(void* const* d_in, const int* in_sizes, int n_in,
                              void* d_out, int out_size, void* d_ws, size_t ws_size,
                              hipStream_t stream) {
    const void* x        = d_in[0];
    const void* pos      = d_in[1];
    const void* cond     = d_in[2];
    const void* w_cond   = d_in[3];
    const void* w_qkv    = d_in[4];
    const void* qk_scale = d_in[5];
    const void* w_out    = d_in[6];

    char* ws = (char*)d_ws;
    constexpr size_t OFS_SCALE = 0;
    constexpr size_t OFS_FLAG  = 8192;
    constexpr size_t OFS_XN    = 16384;
    constexpr size_t OFS_WQKVT = OFS_XN    + 8388608;
    constexpr size_t OFS_WOUTT = OFS_WQKVT + 6291456;
    constexpr size_t OFS_QKV   = OFS_WOUTT + 2097152;
    constexpr size_t OFS_Q     = OFS_QKV   + 25165824;
    constexpr size_t OFS_K     = OFS_Q     + 8388608;
    constexpr size_t OFS_VT    = OFS_K     + 8388608;
    constexpr size_t OFS_O     = OFS_VT    + 8388608;

    float* scale = (float*)(ws + OFS_SCALE);
    int*   flag  = (int*)(ws + OFS_FLAG);
    u16* xn    = (u16*)(ws + OFS_XN);
    u16* wqkvT = (u16*)(ws + OFS_WQKVT);
    u16* woutT = (u16*)(ws + OFS_WOUTT);
    u16* qws   = (u16*)(ws + OFS_Q);
    u16* kws   = (u16*)(ws + OFS_K);
    u16* vtg   = (u16*)(ws + OFS_VT);
    u16* ows   = (u16*)(ws + OFS_O);

    detect_dtype<<<dim3(1), 256, 0, stream>>>((const u16*)x, flag);
    hipMemsetAsync(scale, 0, 2 * 1024 * sizeof(float), stream);
    cond_gemv<<<dim3(4, 2, 16), 256, 0, stream>>>(cond, w_cond, scale, flag);
    rmsnorm_x<<<dim3(4096), 256, 0, stream>>>(x, scale, xn, flag);
    transpose_both<<<dim3(128, 32), 256, 0, stream>>>(w_qkv, wqkvT, w_out, woutT, flag);
    gemm_qkv<<<dim3(24, 32), 256, 0, stream>>>(xn, wqkvT, pos, qk_scale, qws, kws, vtg, flag);
    attn10<<<dim3(8, 32), 1024, 0, stream>>>(qws, kws, vtg, ows);
    gemm_bt64<float><<<dim3(16, 32), 256, 0, stream>>>(ows, woutT, (float*)d_out, 1024, 1024);
}

// Round 13
// 203.632 us; speedup vs baseline: 1.1859x; 1.0288x over previous
//
#include <hip/hip_runtime.h>

typedef unsigned short u16;
typedef unsigned int u32;
typedef short s16x8 __attribute__((ext_vector_type(8)));
typedef short s16x4 __attribute__((ext_vector_type(4)));
typedef float f32x4 __attribute__((ext_vector_type(4)));
typedef float f32x16 __attribute__((ext_vector_type(16)));

#define AS1 __attribute__((address_space(1)))
#define AS3 __attribute__((address_space(3)))

__device__ __forceinline__ float bf2f(u16 u) {
    union { unsigned int i; float f; } x; x.i = ((unsigned int)u) << 16; return x.f;
}
__device__ __forceinline__ u16 f2bf(float f) {
    union { float f; unsigned int i; } x; x.f = f;
    unsigned int r = (x.i + 0x7FFFu + ((x.i >> 16) & 1u)) >> 16;
    return (u16)r;
}
__device__ __forceinline__ void storeOut(u16* p, float v) { *p = f2bf(v); }
__device__ __forceinline__ void storeOut(float* p, float v) { *p = v; }
__device__ __forceinline__ float loadIn(const void* p, size_t i, int isf32) {
    return isf32 ? ((const float*)p)[i] : bf2f(((const u16*)p)[i]);
}
__device__ __forceinline__ float fexp2(float x) {
#if __has_builtin(__builtin_amdgcn_exp2f)
    return __builtin_amdgcn_exp2f(x);
#else
    return exp2f(x);
#endif
}
// exchange upper half-lanes of a with lower half-lanes of b (v_permlane32_swap_b32)
__device__ __forceinline__ void plswap(u32& a, u32& b) {
#if __has_builtin(__builtin_amdgcn_permlane32_swap)
    const auto r = __builtin_amdgcn_permlane32_swap(a, b, false, false);
    a = (u32)r[0]; b = (u32)r[1];
#else
    asm("v_permlane32_swap_b32 %0, %1" : "+v"(a), "+v"(b));
#endif
}

// ---------------- runtime dtype detector + scale zeroing (replaces memset launch) ----
__global__ __launch_bounds__(256) void detect_dtype(const u16* __restrict__ x,
                                                    int* __restrict__ flag,
                                                    float* __restrict__ scale) {
    __shared__ int cnt[4];
    const int tid = threadIdx.x;
    // zero the cond-scale accumulator (2 x 1024 f32) in place of the memset node
    #pragma unroll
    for (int i = 0; i < 8; ++i) scale[tid * 8 + i] = 0.f;
    int c = 0;
    #pragma unroll
    for (int i = 0; i < 4; ++i) {
        const u16 u = x[tid * 4 + i];
        const int e = (u >> 7) & 0xFF;
        c += (e >= 101 && e <= 135) ? 1 : 0;
    }
    #pragma unroll
    for (int m = 1; m < 64; m <<= 1) c += __shfl_xor(c, m, 64);
    if ((tid & 63) == 0) cnt[tid >> 6] = c;
    __syncthreads();
    if (tid == 0) {
        const int t = cnt[0] + cnt[1] + cnt[2] + cnt[3];
        *flag = (t < 800) ? 1 : 0;   // 1 = inputs are float32
    }
}

// ---------------- cond @ w_cond (split-K GEMV, atomicAdd into zeroed f32 ws) ----------
__global__ __launch_bounds__(256) void cond_gemv(const void* __restrict__ cond,
                                                 const void* __restrict__ w,
                                                 float* __restrict__ out,
                                                 const int* __restrict__ flag) {
    const int isf32 = *flag;
    const int d  = blockIdx.x * 256 + threadIdx.x;
    const int n  = blockIdx.y;
    const int k0 = blockIdx.z * 64;
    float acc = 0.f;
    #pragma unroll 8
    for (int k = 0; k < 64; ++k)
        acc += loadIn(cond, n * 1024 + k0 + k, isf32) *
               loadIn(w, (size_t)(k0 + k) * 1024 + d, isf32);
    atomicAdd(out + n * 1024 + d, acc);
}

// ---------------- RMS norm of x with scale = (cond@w_cond + 1) -----------------------
__global__ __launch_bounds__(256) void rmsnorm_x(const void* __restrict__ x,
                                                 const float* __restrict__ scl,
                                                 u16* __restrict__ xn,
                                                 const int* __restrict__ flag) {
    const int isf32 = *flag;
    const int tok = blockIdx.x;
    const int n = tok >> 11;
    u16* orow = xn + (size_t)tok * 1024;
    const int base = threadIdx.x * 4;
    float f0, f1, f2, f3;
    if (isf32) {
        const float4 v = *(const float4*)((const float*)x + (size_t)tok * 1024 + base);
        f0 = v.x; f1 = v.y; f2 = v.z; f3 = v.w;
    } else {
        s16x4 uv = *(const s16x4*)((const u16*)x + (size_t)tok * 1024 + base);
        f0 = bf2f((u16)uv[0]); f1 = bf2f((u16)uv[1]); f2 = bf2f((u16)uv[2]); f3 = bf2f((u16)uv[3]);
    }
    float ss = f0 * f0 + f1 * f1 + f2 * f2 + f3 * f3;
    #pragma unroll
    for (int m = 1; m < 64; m <<= 1) ss += __shfl_xor(ss, m, 64);
    __shared__ float red[4];
    const int wave = threadIdx.x >> 6, lane = threadIdx.x & 63;
    if (lane == 0) red[wave] = ss;
    __syncthreads();
    float ms = (red[0] + red[1] + red[2] + red[3]) * (1.f / 1024.f);
    float rinv = rsqrtf(ms + 1e-6f);
    s16x4 ov;
    ov[0] = (short)f2bf(f0 * (scl[n * 1024 + base + 0] + 1.f) * rinv);
    ov[1] = (short)f2bf(f1 * (scl[n * 1024 + base + 1] + 1.f) * rinv);
    ov[2] = (short)f2bf(f2 * (scl[n * 1024 + base + 2] + 1.f) * rinv);
    ov[3] = (short)f2bf(f3 * (scl[n * 1024 + base + 3] + 1.f) * rinv);
    *(s16x4*)(orow + base) = ov;
}

// ---------------- fused dual transpose (w_qkv 1024x3072 + w_out 1024x1024) -----------
// grid (128, 32): bx < 96 -> w_qkv tile, else w_out tile. One launch instead of two.
__global__ __launch_bounds__(256) void transpose_both(const void* __restrict__ src_qkv,
                                                      u16* __restrict__ dst_qkv,
                                                      const void* __restrict__ src_out,
                                                      u16* __restrict__ dst_out,
                                                      const int* __restrict__ flag) {
    const int isf32 = *flag;
    __shared__ u16 t[32][33];
    const void* src; u16* dst; int C, c0;
    const int R = 1024;
    if (blockIdx.x < 96) { src = src_qkv; dst = dst_qkv; C = 3072; c0 = blockIdx.x * 32; }
    else                 { src = src_out; dst = dst_out; C = 1024; c0 = (blockIdx.x - 96) * 32; }
    const int r0 = blockIdx.y * 32;
    const int tx = threadIdx.x & 31, ty = threadIdx.x >> 5;
    #pragma unroll
    for (int i = 0; i < 4; ++i)
        t[ty + i * 8][tx] = f2bf(loadIn(src, (size_t)(r0 + ty + i * 8) * C + c0 + tx, isf32));
    __syncthreads();
    #pragma unroll
    for (int i = 0; i < 4; ++i)
        dst[(size_t)(c0 + ty + i * 8) * R + r0 + tx] = t[tx][ty + i * 8];
}

// ---------------- fused qkv GEMM + per-head RMS/RoPE/V-transpose epilogue ------------
// C[M=4096, N=3072] = xn[4096,1024] * wqkvT[3072,1024]^T, 128x128 tile, BK=32,
// dbuf LDS + counted vmcnt(4). Epilogue consumes acc directly (qkv never hits HBM):
//   bx<8 q: RMS+qmul+RoPE -> qws ; bx<16 k: RMS+RoPE -> kws ; bx>=16 v: LDS
//   transpose -> vtg. (Proven in round 12.)
__global__ __launch_bounds__(256) void gemm_qkv(const u16* __restrict__ A,
                                                const u16* __restrict__ BT,
                                                const void* __restrict__ pos,
                                                const void* __restrict__ qk_scale,
                                                u16* __restrict__ qws,
                                                u16* __restrict__ kws,
                                                u16* __restrict__ vtg,
                                                const int* __restrict__ flag) {
    constexpr int K = 1024;
    __shared__ u16 sbuf[128 * 136];            // 34 KB; staging uses first 32 KB
    u16* As = sbuf;                            // [2][128*32]
    u16* Bs = sbuf + 8192;                     // [2][128*32]
    const int tid = threadIdx.x;
    const int wave = tid >> 6, lane = tid & 63;
    const int l15 = lane & 15, quad = lane >> 4;
    const int bm0 = blockIdx.y * 128, bn0 = blockIdx.x * 128;
    const int wr = wave >> 1, wc = wave & 1;
    f32x4 acc[4][4] = {};
    const int srow = lane >> 2;
    const int g = (lane & 3) ^ (srow & 3);

    auto stageg = [&](int ck, int slot) {
        const int bk = ck * 32;
        #pragma unroll
        for (int p = 0; p < 2; ++p) {
            const int rowl = p * 64 + wave * 16 + srow;
            const u16* ga = A + (size_t)(bm0 + rowl) * K + bk + g * 8;
            u16* la = As + slot * 4096 + (p * 64 + wave * 16) * 32;
            __builtin_amdgcn_global_load_lds((const AS1 void*)ga, (AS3 void*)la, 16, 0, 0);
            const u16* gb = BT + (size_t)(bn0 + rowl) * K + bk + g * 8;
            u16* lb = Bs + slot * 4096 + (p * 64 + wave * 16) * 32;
            __builtin_amdgcn_global_load_lds((const AS1 void*)gb, (AS3 void*)lb, 16, 0, 0);
        }
    };

    const int NC = K >> 5;
    stageg(0, 0);
    for (int j = 0; j < NC; ++j) {
        if (j > 0) __builtin_amdgcn_s_barrier();
        if (j < NC - 1) {
            stageg(j + 1, (j + 1) & 1);
            asm volatile("s_waitcnt vmcnt(4)" ::: "memory");
        } else {
            asm volatile("s_waitcnt vmcnt(0)" ::: "memory");
        }
        __builtin_amdgcn_sched_barrier(0);
        __builtin_amdgcn_s_barrier();

        const u16* Ac = As + (j & 1) * 4096;
        const u16* Bc = Bs + (j & 1) * 4096;
        s16x8 af[4], bfr[4];
        #pragma unroll
        for (int mt = 0; mt < 4; ++mt) {
            const int r = wr * 64 + mt * 16 + l15;
            af[mt] = *(const s16x8*)(Ac + r * 32 + ((quad ^ (r & 3)) << 3));
        }
        #pragma unroll
        for (int nt = 0; nt < 4; ++nt) {
            const int r = wc * 64 + nt * 16 + l15;
            bfr[nt] = *(const s16x8*)(Bc + r * 32 + ((quad ^ (r & 3)) << 3));
        }
        #pragma unroll
        for (int mt = 0; mt < 4; ++mt)
            #pragma unroll
            for (int nt = 0; nt < 4; ++nt)
                acc[mt][nt] = __builtin_amdgcn_mfma_f32_16x16x32_bf16(af[mt], bfr[nt], acc[mt][nt], 0, 0, 0);
    }

    // ---------------- fused epilogue ----------------
    const int isf32 = *flag;
    const int bx = blockIdx.x;
    const int rowbase = bm0 + wr * 64;
    const int n = rowbase >> 11;               // batch (64-row band never crosses 2048)
    const int colw = bn0 + wc * 64;            // this wave's 64-col head span

    if (bx < 16) {
        // ---- q (bx<8) or k: per-row RMS + RoPE, write to head-major layout ----
        const int isq = (bx < 8);
        const int hh = (colw >> 6) & 15;
        float mul = 1.f;
        if (isq) {
            const float qs = loadIn(qk_scale, hh, isf32);
            const float s = __expf(0.5f * fminf(qs, 4.605170186f) - 1.039720771f);
            mul = s * s * 0.125f * 1.44269504089f;
        }
        const float t = (float)(l15 * 16 + hh);
        const float freq = 3.14159265358979f * __expf(t * (2.302585093f / 256.f));
        u16* dstb = (isq ? qws : kws) + (size_t)(n * 16 + hh) * 2048 * 64;
        #pragma unroll
        for (int mt = 0; mt < 4; ++mt)
            #pragma unroll
            for (int rr = 0; rr < 4; ++rr) {
                const int row = rowbase + mt * 16 + quad * 4 + rr;   // global token
                const int l = row & 2047;
                float s2 = acc[mt][0][rr] * acc[mt][0][rr] + acc[mt][1][rr] * acc[mt][1][rr]
                         + acc[mt][2][rr] * acc[mt][2][rr] + acc[mt][3][rr] * acc[mt][3][rr];
                #pragma unroll
                for (int m = 1; m < 16; m <<= 1) s2 += __shfl_xor(s2, m, 16);
                const float sc = rsqrtf(s2 * (1.f / 64.f) + 1e-6f) * mul;
                const float p0 = loadIn(pos, (size_t)row * 2 + 0, isf32);
                const float p1 = loadIn(pos, (size_t)row * 2 + 1, isf32);
                const float c0 = __cosf(p0 * freq), sn0 = __sinf(p0 * freq);
                const float c1 = __cosf(p1 * freq), sn1 = __sinf(p1 * freq);
                const float a0 = acc[mt][0][rr] * sc, a1 = acc[mt][1][rr] * sc;
                const float a2 = acc[mt][2][rr] * sc, a3 = acc[mt][3][rr] * sc;
                u16* d = dstb + (size_t)l * 64 + l15;
                d[0]  = f2bf(a0 * c0 - a2 * sn0);    // e = l15      (pj=0, -sin)
                d[16] = f2bf(a1 * c1 - a3 * sn1);    // e = 16+l15   (pj=1, -sin)
                d[32] = f2bf(a2 * c0 + a0 * sn0);    // e = 32+l15   (pj=0, +sin)
                d[48] = f2bf(a3 * c1 + a1 * sn1);    // e = 48+l15   (pj=1, +sin)
            }
    } else {
        // ---- v: transpose via LDS (reuse staging buffer), write vtg[nh][e][l] ----
        __syncthreads();                       // all waves done with staging LDS
        #pragma unroll
        for (int mt = 0; mt < 4; ++mt)
            #pragma unroll
            for (int nt = 0; nt < 4; ++nt)
                #pragma unroll
                for (int rr = 0; rr < 4; ++rr)
                    sbuf[(wc * 64 + nt * 16 + l15) * 136 + (wr * 64 + mt * 16 + quad * 4 + rr)]
                        = f2bf(acc[mt][nt][rr]);
        __syncthreads();
        const int ec = tid >> 1, half = tid & 1;           // tile col 0..127, row half
        const int vcol = bn0 + ec - 2048;                  // v-dim global col
        const int hh = vcol >> 6, e = vcol & 63;
        const int lbase = (bm0 & 2047) + half * 64;
        u16* d = vtg + ((size_t)((bm0 >> 11) * 16 + hh) * 64 + e) * 2048 + lbase;
        #pragma unroll
        for (int i = 0; i < 8; ++i)
            *(s16x8*)(d + i * 8) = *(const s16x8*)(sbuf + ec * 136 + half * 64 + i * 8);
    }
}

// ---------------- bf16 GEMM, 128x64 tile (2 blocks/CU for the narrow out-GEMM) -------
template <typename OutT>
__global__ __launch_bounds__(256) void gemm_bt64(const u16* __restrict__ A,
                                                 const u16* __restrict__ BT,
                                                 OutT* __restrict__ C, int Nn, int K) {
    __shared__ u16 As[2][128 * 32];
    __shared__ u16 Bs[2][64 * 32];
    const int tid = threadIdx.x;
    const int wave = tid >> 6, lane = tid & 63;
    const int l15 = lane & 15, quad = lane >> 4;
    const int bm0 = blockIdx.y * 128, bn0 = blockIdx.x * 64;
    const int wr = wave >> 1, wc = wave & 1;
    f32x4 acc[4][2] = {};
    const int srow = lane >> 2;
    const int g = (lane & 3) ^ (srow & 3);

    auto stageg = [&](int ck, int slot) {
        const int bk = ck * 32;
        #pragma unroll
        for (int p = 0; p < 2; ++p) {
            const int rowl = p * 64 + wave * 16 + srow;
            const u16* ga = A + (size_t)(bm0 + rowl) * K + bk + g * 8;
            u16* la = As[slot] + (p * 64 + wave * 16) * 32;
            __builtin_amdgcn_global_load_lds((const AS1 void*)ga, (AS3 void*)la, 16, 0, 0);
        }
        {
            const int rowl = wave * 16 + srow;
            const u16* gb = BT + (size_t)(bn0 + rowl) * K + bk + g * 8;
            u16* lb = Bs[slot] + (wave * 16) * 32;
            __builtin_amdgcn_global_load_lds((const AS1 void*)gb, (AS3 void*)lb, 16, 0, 0);
        }
    };

    const int NC = K >> 5;
    stageg(0, 0);
    for (int j = 0; j < NC; ++j) {
        if (j > 0) __builtin_amdgcn_s_barrier();
        if (j < NC - 1) {
            stageg(j + 1, (j + 1) & 1);
            asm volatile("s_waitcnt vmcnt(3)" ::: "memory");
        } else {
            asm volatile("s_waitcnt vmcnt(0)" ::: "memory");
        }
        __builtin_amdgcn_sched_barrier(0);
        __builtin_amdgcn_s_barrier();

        const u16* Ac = As[j & 1];
        const u16* Bc = Bs[j & 1];
        s16x8 af[4], bfr[2];
        #pragma unroll
        for (int mt = 0; mt < 4; ++mt) {
            const int r = wr * 64 + mt * 16 + l15;
            af[mt] = *(const s16x8*)(Ac + r * 32 + ((quad ^ (r & 3)) << 3));
        }
        #pragma unroll
        for (int nt = 0; nt < 2; ++nt) {
            const int r = wc * 32 + nt * 16 + l15;
            bfr[nt] = *(const s16x8*)(Bc + r * 32 + ((quad ^ (r & 3)) << 3));
        }
        #pragma unroll
        for (int mt = 0; mt < 4; ++mt)
            #pragma unroll
            for (int nt = 0; nt < 2; ++nt)
                acc[mt][nt] = __builtin_amdgcn_mfma_f32_16x16x32_bf16(af[mt], bfr[nt], acc[mt][nt], 0, 0, 0);
    }
    #pragma unroll
    for (int mt = 0; mt < 4; ++mt)
        #pragma unroll
        for (int nt = 0; nt < 2; ++nt)
            #pragma unroll
            for (int r = 0; r < 4; ++r) {
                const int row = bm0 + wr * 64 + mt * 16 + quad * 4 + r;
                const int col = bn0 + wc * 32 + nt * 16 + l15;
                storeOut(C + (size_t)row * Nn + col, acc[mt][nt][r]);
            }
}

// ---------------- flash attention v10x: attn10 + XCD-locality grid swap --------------
// SINGLE change vs proven attn10: grid is now (32 heads, 8 q-blocks) so linear block
// id = nh + 32*qb -> XCD = id%8 = nh%8: all 8 q-blocks of a head share ONE XCD's L2
// (4 heads/XCD). Old layout spread each head over all 8 XCDs -> 8x K/V HBM re-fetch
// (FETCH 70 MB vs 24 MB ideal). Kernel body identical; only nh/q0 sourcing swapped.
__global__ __launch_bounds__(1024) void attn10(const u16* __restrict__ Q,
                                               const u16* __restrict__ K,
                                               const u16* __restrict__ Vtg,
                                               u16* __restrict__ O) {
    __shared__ u16 Ks[2][256 * 64];   // chunk rows x 64 e (128 B rows)
    __shared__ u16 Vt[2][64 * 256];   // 64 e-rows x chunk cols (512 B rows)
    const int nh = blockIdx.x;                    // <- swapped (XCD = nh % 8)
    const int q0 = blockIdx.y * 256;              // <- swapped
    const int tid = threadIdx.x;
    const int wave = tid >> 6, lane = tid & 63;
    const int wq = wave & 7, ks = wave >> 3;
    const int l31 = lane & 31, h = lane >> 5;
    const size_t hb = (size_t)nh * 2048 * 64;
    const u16* Vbase = Vtg + (size_t)nh * 131072;

    // Q fragments (B-operand of 32x32x16: col=q=l31, rows e=kd*16+h*8+0..7)
    s16x8 qf[4];
    #pragma unroll
    for (int kd = 0; kd < 4; ++kd)
        qf[kd] = *(const s16x8*)(Q + hb + (size_t)(q0 + wq * 32 + l31) * 64 + kd * 16 + h * 8);

    f32x16 Oacc[2] = {};
    float lacc = 0.f;

    // stage one 256-key chunk across 16 waves: K 32 KB (2 rounds of 128 rows) +
    // V 32 KB (2 rounds of 32 e-rows) = 4 global_load_lds per thread.
    auto stage = [&](int ch, int slot) {
        const int kb = ch * 256;
        #pragma unroll
        for (int r = 0; r < 2; ++r) {
            const int row = r * 128 + (tid >> 3);
            const int g = (tid & 7) ^ (row & 7);
            __builtin_amdgcn_global_load_lds(
                (const AS1 void*)(K + hb + (size_t)(kb + row) * 64 + g * 8),
                (AS3 void*)(Ks[slot] + (r * 128 + wave * 8) * 64), 16, 0, 0);
        }
        #pragma unroll
        for (int r = 0; r < 2; ++r) {
            const int er = r * 32 + (tid >> 5);
            const int g2 = (lane & 31) ^ (er & 7);
            __builtin_amdgcn_global_load_lds(
                (const AS1 void*)(Vbase + (size_t)er * 2048 + kb + g2 * 8),
                (AS3 void*)(Vt[slot] + (r * 32 + wave * 2) * 256), 16, 0, 0);
        }
    };

    stage(0, 0);

    for (int j = 0; j < 8; ++j) {
        // top barrier: all waves finished reading buf[(j+1)&1] (used by chunk j-1)
        if (j > 0) __builtin_amdgcn_s_barrier();
        if (j < 7) {
            stage(j + 1, (j + 1) & 1);
            // wait for chunk j's 4 loads (oldest); 4 newest (chunk j+1) stay in flight
            asm volatile("s_waitcnt vmcnt(4)" ::: "memory");
        } else {
            asm volatile("s_waitcnt vmcnt(0)" ::: "memory");
        }
        __builtin_amdgcn_sched_barrier(0);
        __builtin_amdgcn_s_barrier();   // all waves' chunk-j rows present in LDS

        const u16* Kt = Ks[j & 1];
        const u16* Vc = Vt[j & 1];

        #pragma unroll 2
        for (int t = 0; t < 4; ++t) {
            const int kt = ks * 4 + t;   // this wave-group's kt-half
            // ---- QK: S^T(32k x 32q) = K-slice * Q^T, contraction e=64 in 4 steps ----
            f32x16 S;
            #pragma unroll
            for (int jj = 0; jj < 16; ++jj) S[jj] = -15.f;
            const int kr = kt * 32 + l31;
            __builtin_amdgcn_s_setprio(1);
            #pragma unroll
            for (int kd = 0; kd < 4; ++kd) {
                const s16x8 kf = *(const s16x8*)(Kt + kr * 64 + ((((kd << 1) + h) ^ (kr & 7)) << 3));
                S = __builtin_amdgcn_mfma_f32_32x32x16_bf16(kf, qf[kd], S, 0, 0, 0);
            }
            __builtin_amdgcn_s_setprio(0);
            // ---- softmax: exp2 (shift -15 in acc init), row-sum partial ----
            float e[16];
            #pragma unroll
            for (int jj = 0; jj < 16; ++jj) e[jj] = fexp2(S[jj]);
            float rs = 0.f;
            #pragma unroll
            for (int jj = 0; jj < 16; ++jj) rs += e[jj];
            lacc += rs;
            // ---- pack P to bf16 pairs + half-swap into PV A-fragments ----
            u32 c[8];
            #pragma unroll
            for (int jj = 0; jj < 8; ++jj)
                asm("v_cvt_pk_bf16_f32 %0, %1, %2" : "=v"(c[jj]) : "v"(e[2 * jj]), "v"(e[2 * jj + 1]));
            plswap(c[0], c[2]);
            plswap(c[1], c[3]);
            plswap(c[4], c[6]);
            plswap(c[5], c[7]);
            union { u32 u[4]; s16x8 v; } pfa, pfb;
            pfa.u[0] = c[0]; pfa.u[1] = c[1]; pfa.u[2] = c[2]; pfa.u[3] = c[3];
            pfb.u[0] = c[4]; pfb.u[1] = c[5]; pfb.u[2] = c[6]; pfb.u[3] = c[7];
            // ---- PV: Oacc(32q x 32e per et) += P(32q x 32k) * V(32k x 32e) ----
            __builtin_amdgcn_s_setprio(1);
            #pragma unroll
            for (int et = 0; et < 2; ++et) {
                const int er = et * 32 + l31;
                #pragma unroll
                for (int kdp = 0; kdp < 2; ++kdp) {
                    const int ch = kt * 4 + kdp * 2 + h;
                    const s16x8 vf = *(const s16x8*)(Vc + er * 256 + ((ch ^ (er & 7)) << 3));
                    Oacc[et] = __builtin_amdgcn_mfma_f32_32x32x16_bf16(kdp ? pfb.v : pfa.v, vf, Oacc[et], 0, 0, 0);
                }
            }
            __builtin_amdgcn_s_setprio(0);
        }
    }

    // ---- combine the two kt-half groups: pure add (fixed-shift softmax, no max) ----
    __syncthreads();   // all waves done reading Ks/Vt -> safe to overlay
    float (*Osh)[512] = (float(*)[512]) & Ks[0][0];   // 32 x 512 f32 = 64 KB
    float* Lsh = (float*)&Vt[0][0];                   // 512 f32
    if (ks == 1) {
        #pragma unroll
        for (int et = 0; et < 2; ++et)
            #pragma unroll
            for (int r = 0; r < 16; ++r)
                Osh[et * 16 + r][wq * 64 + lane] = Oacc[et][r];
        Lsh[wq * 64 + lane] = lacc;
    }
    __syncthreads();
    if (ks == 0) {
        #pragma unroll
        for (int et = 0; et < 2; ++et)
            #pragma unroll
            for (int r = 0; r < 16; ++r)
                Oacc[et][r] += Osh[et * 16 + r][wq * 64 + lane];
        lacc += Lsh[wq * 64 + lane];

        // ---- epilogue: combine row-sums across lane halves, normalize, store ----
        lacc += __shfl_xor(lacc, 32, 64);
        const float linv_l = 1.f / lacc;   // lane l31 holds 1/l for q = l31
        const int n = nh >> 4, hh = nh & 15;
        #pragma unroll
        for (int r = 0; r < 16; ++r) {
            const int ql = (r & 3) + 8 * (r >> 2) + 4 * h;   // q-row of D-reg r
            const float linv = __shfl(linv_l, ql, 64);
            const int qrow = q0 + wq * 32 + ql;
            #pragma unroll
            for (int et = 0; et < 2; ++et)
                O[((size_t)n * 2048 + qrow) * 1024 + hh * 64 + et * 32 + l31] = f2bf(Oacc[et][r] * linv);
        }
    }
}

// ---------------- launch --------------------------------------------------------------
extern "C" void kernel_launch(void* const* d_in, const int* in_sizes, int n_in,
                              void* d_out, int out_size, void* d_ws, size_t ws_size,
                              hipStream_t stream) {
    const void* x        = d_in[0];
    const void* pos      = d_in[1];
    const void* cond     = d_in[2];
    const void* w_cond   = d_in[3];
    const void* w_qkv    = d_in[4];
    const void* qk_scale = d_in[5];
    const void* w_out    = d_in[6];

    char* ws = (char*)d_ws;
    constexpr size_t OFS_SCALE = 0;
    constexpr size_t OFS_FLAG  = 8192;
    constexpr size_t OFS_XN    = 16384;
    constexpr size_t OFS_WQKVT = OFS_XN    + 8388608;
    constexpr size_t OFS_WOUTT = OFS_WQKVT + 6291456;
    constexpr size_t OFS_QKV   = OFS_WOUTT + 2097152;
    constexpr size_t OFS_Q     = OFS_QKV   + 25165824;
    constexpr size_t OFS_K     = OFS_Q     + 8388608;
    constexpr size_t OFS_VT    = OFS_K     + 8388608;
    constexpr size_t OFS_O     = OFS_VT    + 8388608;

    float* scale = (float*)(ws + OFS_SCALE);
    int*   flag  = (int*)(ws + OFS_FLAG);
    u16* xn    = (u16*)(ws + OFS_XN);
    u16* wqkvT = (u16*)(ws + OFS_WQKVT);
    u16* woutT = (u16*)(ws + OFS_WOUTT);
    u16* qws   = (u16*)(ws + OFS_Q);
    u16* kws   = (u16*)(ws + OFS_K);
    u16* vtg   = (u16*)(ws + OFS_VT);
    u16* ows   = (u16*)(ws + OFS_O);

    detect_dtype<<<dim3(1), 256, 0, stream>>>((const u16*)x, flag, scale);
    cond_gemv<<<dim3(4, 2, 16), 256, 0, stream>>>(cond, w_cond, scale, flag);
    rmsnorm_x<<<dim3(4096), 256, 0, stream>>>(x, scale, xn, flag);
    transpose_both<<<dim3(128, 32), 256, 0, stream>>>(w_qkv, wqkvT, w_out, woutT, flag);
    gemm_qkv<<<dim3(24, 32), 256, 0, stream>>>(xn, wqkvT, pos, qk_scale, qws, kws, vtg, flag);
    attn10<<<dim3(32, 8), 1024, 0, stream>>>(qws, kws, vtg, ows);
    gemm_bt64<float><<<dim3(16, 32), 256, 0, stream>>>(ows, woutT, (float*)d_out, 1024, 1024);
}